// Round 1
// baseline (581.546 us; speedup 1.0000x reference)
//
#include <hip/hip_runtime.h>
#include <math.h>

#define BB 2
#define HH 64
#define WW 64
#define CC 96
#define DIN 192
#define NST 16
#define RNK 6
#define KK 4
#define LL 4096
#define RTOT (RNK + 2*NST)   // 38
#define SEG 16
#define SEGLEN (LL/SEG)      // 256

// ---------------------------------------------------------------------------
// K1: in_proj  xz = x @ W_in^T ; xc -> (b,d,l) channel-major ; z -> silu -> (b,d,l)
// block: 256 thr, tile = 64 l positions; grid (L/64, B)
__global__ __launch_bounds__(256) void k_inproj(const float* __restrict__ x,
        const float* __restrict__ W_in, float* __restrict__ xc_pre,
        float* __restrict__ z_silu) {
    __shared__ float lx[96*65];            // [c][l], pad 65 to kill conflicts
    int b = blockIdx.y;
    int l0 = blockIdx.x * 64;
    int t = threadIdx.x;
    for (int i = 0; i < 24; ++i) {
        int e = t + 256*i;                 // 64*96 = 6144 elems
        int l = e / 96, c = e % 96;
        lx[c*65 + l] = x[((size_t)(b*LL + l0 + l))*96 + c];
    }
    __syncthreads();
    int l = t & 63;
    int ocg = __builtin_amdgcn_readfirstlane(t >> 6);   // wave-uniform -> s_load weights
    for (int ch = 0; ch < 6; ++ch) {
        int oc0 = ocg*96 + ch*16;
        float acc[16];
        #pragma unroll
        for (int q = 0; q < 16; ++q) acc[q] = 0.f;
        for (int c = 0; c < 96; ++c) {
            float xv = lx[c*65 + l];
            #pragma unroll
            for (int q = 0; q < 16; ++q) acc[q] += xv * W_in[(oc0+q)*96 + c];
        }
        #pragma unroll
        for (int q = 0; q < 16; ++q) {
            int oc = oc0 + q;
            float v = acc[q];
            if (oc < DIN) {
                xc_pre[((size_t)(b*DIN + oc))*LL + l0 + l] = v;
            } else {
                z_silu[((size_t)(b*DIN + oc - DIN))*LL + l0 + l] = v / (1.f + __expf(-v));
            }
        }
    }
}

// ---------------------------------------------------------------------------
// K2: depthwise 3x3 conv (SAME) + bias + SiLU
__global__ __launch_bounds__(256) void k_conv(const float* __restrict__ xc,
        const float* __restrict__ cw, const float* __restrict__ cb,
        float* __restrict__ out) {
    int idx = blockIdx.x*256 + threadIdx.x;     // (b,d,h,w)
    int w = idx & 63;
    int h = (idx >> 6) & 63;
    int d = (idx >> 12) % DIN;
    int b = idx / (4096*DIN);
    const float* src = xc + ((size_t)(b*DIN + d))*LL;
    float acc = cb[d];
    #pragma unroll
    for (int dh = -1; dh <= 1; ++dh) {
        int h2 = h + dh;
        bool okh = (h2 >= 0) && (h2 < 64);
        #pragma unroll
        for (int dw = -1; dw <= 1; ++dw) {
            int w2 = w + dw;
            if (okh && w2 >= 0 && w2 < 64)
                acc += src[h2*64 + w2] * cw[d*9 + (dh+1)*3 + (dw+1)];
        }
    }
    out[((size_t)(b*DIN + d))*LL + h*64 + w] = acc / (1.f + __expf(-acc));
}

// ---------------------------------------------------------------------------
// K3: per (b,k,l): gather xs, x_dbl = xpw @ xs -> dts/Bs/Cs ; delta = softplus(dts@dt_w + dt_b)
// block: 256 thr, tile = 64 l; grid (L/64, K, B)
__global__ __launch_bounds__(256) void k_proj(const float* __restrict__ xconv,
        const int* __restrict__ scan_ids,
        const float* __restrict__ xpw, const float* __restrict__ dtw,
        const float* __restrict__ dtb,
        float* __restrict__ Bs, float* __restrict__ Cs, float* __restrict__ delta) {
    __shared__ float lxs[DIN*65];     // [d][l]
    __shared__ float ldts[RNK*64];
    __shared__ int lsid[64];
    int k = blockIdx.y, b = blockIdx.z;
    int l0 = blockIdx.x * 64;
    int t = threadIdx.x;
    if (t < 64) lsid[t] = scan_ids[k*LL + l0 + t];
    __syncthreads();
    for (int i = 0; i < 48; ++i) {
        int e = t + 256*i;            // 192*64 elems
        int d = e >> 6, l = e & 63;
        lxs[d*65 + l] = xconv[((size_t)(b*DIN + d))*LL + lsid[l]];
    }
    __syncthreads();
    int l = t & 63;
    int rg = __builtin_amdgcn_readfirstlane(t >> 6);    // wave-uniform row group
    float acc[10];
    #pragma unroll
    for (int j = 0; j < 10; ++j) acc[j] = 0.f;
    for (int d = 0; d < DIN; ++d) {
        float xv = lxs[d*65 + l];
        #pragma unroll
        for (int j = 0; j < 10; ++j) {
            int r = rg + 4*j;
            if (r < RTOT) acc[j] += xv * xpw[(k*RTOT + r)*DIN + d];
        }
    }
    #pragma unroll
    for (int j = 0; j < 10; ++j) {
        int r = rg + 4*j;
        if (r < RTOT) {
            float a = acc[j];
            if (r < RNK)           ldts[r*64 + l] = a;
            else if (r < RNK+NST)  Bs[((size_t)((b*KK+k)*LL + l0 + l))*NST + (r-RNK)] = a;
            else                   Cs[((size_t)((b*KK+k)*LL + l0 + l))*NST + (r-RNK-NST)] = a;
        }
    }
    __syncthreads();
    for (int j = 0; j < 48; ++j) {
        int d = rg + 4*j;
        float a = dtb[k*DIN + d];
        #pragma unroll
        for (int r = 0; r < RNK; ++r)
            a += ldts[r*64 + l] * dtw[(k*DIN + d)*RNK + r];
        float sp = (a > 15.f) ? a : log1pf(__expf(a));
        delta[((size_t)((b*KK+k)*DIN + d))*LL + l0 + l] = sp;
    }
}

// ---------------------------------------------------------------------------
// K4: scan pass 1 — per-segment (prod dA, partial state with h0=0)
// block 256 = 16 d x 16 n ; grid (SEG, DIN/16, B*K)
__global__ __launch_bounds__(256) void k_scan1(const float* __restrict__ delta,
        const float* __restrict__ xconv, const float* __restrict__ Bs,
        const int* __restrict__ scan_ids, const float* __restrict__ A_logs,
        float* __restrict__ segA, float* __restrict__ segB) {
    __shared__ float ldel[16*SEGLEN];
    __shared__ float lxg[16*SEGLEN];
    __shared__ float lB[SEGLEN*NST];
    __shared__ int lsid[SEGLEN];
    int seg = blockIdx.x, dg = blockIdx.y, bk = blockIdx.z;
    int b = bk >> 2, k = bk & 3;
    int t = threadIdx.x;
    int l0 = seg * SEGLEN;
    int d0 = dg * 16;
    lsid[t] = scan_ids[k*LL + l0 + t];
    __syncthreads();
    for (int i = 0; i < 16; ++i) {
        int ee = t + 256*i;                    // dl = ee>>8, li = ee&255
        int dl = ee >> 8, li = ee & 255;
        ldel[ee] = delta[((size_t)(bk*DIN + d0 + dl))*LL + l0 + li];
        lxg[ee]  = xconv[((size_t)(b*DIN + d0 + dl))*LL + lsid[li]];
        lB[ee]   = Bs[((size_t)(bk*LL + l0))*NST + ee];
    }
    __syncthreads();
    int n = t & 15, dl = t >> 4;
    float Av = -__expf(A_logs[(k*DIN + d0 + dl)*NST + n]);
    float h = 0.f, a = 1.f;
    for (int li = 0; li < SEGLEN; ++li) {
        float dv = ldel[dl*SEGLEN + li];
        float xv = lxg[dl*SEGLEN + li];
        float bv = lB[li*NST + n];
        float e = __expf(dv * Av);
        h = e*h + dv*xv*bv;
        a *= e;
    }
    size_t o = (((size_t)bk*SEG + seg)*DIN + (d0 + dl))*NST + n;
    segA[o] = a;
    segB[o] = h;
}

// ---------------------------------------------------------------------------
// K5: scan pass 2 — compose segment carries (16 sequential steps)
__global__ __launch_bounds__(256) void k_scan2(const float* __restrict__ segA,
        const float* __restrict__ segB, float* __restrict__ hinit) {
    int idx = blockIdx.x*256 + threadIdx.x;   // (bk, d*NST+n)
    int bk = idx / (DIN*NST);
    int dn = idx % (DIN*NST);
    float h = 0.f;
    for (int s = 0; s < SEG; ++s) {
        size_t o = ((size_t)(bk*SEG + s))*DIN*NST + dn;
        hinit[o] = h;
        h = segA[o]*h + segB[o];
    }
}

// ---------------------------------------------------------------------------
// K6: scan pass 3 — replay with correct h0, y = sum_n h*C + xs*D, scatter via scan_ids,
// accumulate pool sums for gating.
__global__ __launch_bounds__(256) void k_scan3(const float* __restrict__ delta,
        const float* __restrict__ xconv, const float* __restrict__ Bs,
        const float* __restrict__ Cs,
        const int* __restrict__ scan_ids, const float* __restrict__ A_logs,
        const float* __restrict__ Ds, const float* __restrict__ hinit,
        float* __restrict__ y_dirs, float* __restrict__ poolsum) {
    __shared__ float ldel[16*SEGLEN];
    __shared__ float lxg[16*SEGLEN];
    __shared__ float lB[SEGLEN*NST];
    __shared__ float lC[SEGLEN*NST];
    __shared__ int lsid[SEGLEN];
    int seg = blockIdx.x, dg = blockIdx.y, bk = blockIdx.z;
    int b = bk >> 2, k = bk & 3;
    int t = threadIdx.x;
    int l0 = seg * SEGLEN;
    int d0 = dg * 16;
    lsid[t] = scan_ids[k*LL + l0 + t];
    __syncthreads();
    for (int i = 0; i < 16; ++i) {
        int ee = t + 256*i;
        int dl = ee >> 8, li = ee & 255;
        ldel[ee] = delta[((size_t)(bk*DIN + d0 + dl))*LL + l0 + li];
        lxg[ee]  = xconv[((size_t)(b*DIN + d0 + dl))*LL + lsid[li]];
        lB[ee]   = Bs[((size_t)(bk*LL + l0))*NST + ee];
        lC[ee]   = Cs[((size_t)(bk*LL + l0))*NST + ee];
    }
    __syncthreads();
    int n = t & 15, dl = t >> 4;
    int d = d0 + dl;
    float Av = -__expf(A_logs[(k*DIN + d)*NST + n]);
    float Dv = Ds[k*DIN + d];
    float h = hinit[(((size_t)bk*SEG + seg)*DIN + d)*NST + n];
    float pool = 0.f;
    for (int li = 0; li < SEGLEN; ++li) {
        float dv = ldel[dl*SEGLEN + li];
        float xv = lxg[dl*SEGLEN + li];
        float bv = lB[li*NST + n];
        float cv = lC[li*NST + n];
        float e = __expf(dv * Av);
        h = e*h + dv*xv*bv;
        float p = h * cv;
        p += __shfl_xor(p, 1);
        p += __shfl_xor(p, 2);
        p += __shfl_xor(p, 4);
        p += __shfl_xor(p, 8);
        if (n == 0) {
            float yv = p + xv*Dv;
            y_dirs[((size_t)(bk*DIN + d))*LL + lsid[li]] = yv;   // scatter = inverse gather
            pool += yv;
        }
    }
    if (n == 0) atomicAdd(&poolsum[(b*DIN + d)*KK + k], pool);
}

// ---------------------------------------------------------------------------
// K7: gate = sigmoid(pooled @ gate_w + gate_b), grouped per channel g
__global__ void k_gate(const float* __restrict__ poolsum, const float* __restrict__ gw,
        const float* __restrict__ gb, float* __restrict__ gate) {
    int idx = blockIdx.x*256 + threadIdx.x;   // (b*DIN+d)*K + o
    int o = idx & 3;
    int bd = idx >> 2;
    int d = bd % DIN;
    float acc = gb[d*KK + o];
    #pragma unroll
    for (int i = 0; i < KK; ++i)
        acc += (poolsum[bd*KK + i] * (1.f/LL)) * gw[(d*KK + o)*KK + i];
    gate[idx] = 1.f/(1.f + __expf(-acc));
}

// ---------------------------------------------------------------------------
// K8: y = sum_k gate*y_dirs ; LayerNorm(d) ; * silu(z) ; @ W_out^T
// block 256, tile = 16 l ; grid (L/16, B)
__global__ __launch_bounds__(256) void k_final(const float* __restrict__ y_dirs,
        const float* __restrict__ gate, const float* __restrict__ z_silu,
        const float* __restrict__ lng, const float* __restrict__ lnb,
        const float* __restrict__ Wout, float* __restrict__ out) {
    __shared__ float buf[16*193];     // [l][d]
    __shared__ float lmu[16], lrs[16];
    int b = blockIdx.y;
    int l0 = blockIdx.x * 16;
    int t = threadIdx.x;
    int l = t & 15, g = t >> 4;
    for (int j = 0; j < 12; ++j) {
        int d = g + 16*j;
        float acc = 0.f;
        #pragma unroll
        for (int k = 0; k < KK; ++k)
            acc += y_dirs[((size_t)((b*KK + k)*DIN + d))*LL + l0 + l] * gate[(b*DIN + d)*KK + k];
        buf[l*193 + d] = acc;
    }
    __syncthreads();
    // stats: l2 = t>>4 (16 l), q = t&15 lanes reduce width-16
    int l2 = t >> 4, q = t & 15;
    float s = 0.f, s2 = 0.f;
    for (int i = 0; i < 12; ++i) {
        float v = buf[l2*193 + q + 16*i];
        s += v; s2 += v*v;
    }
    s += __shfl_xor(s, 1);  s2 += __shfl_xor(s2, 1);
    s += __shfl_xor(s, 2);  s2 += __shfl_xor(s2, 2);
    s += __shfl_xor(s, 4);  s2 += __shfl_xor(s2, 4);
    s += __shfl_xor(s, 8);  s2 += __shfl_xor(s2, 8);
    if (q == 0) {
        float mu = s * (1.f/DIN);
        float var = s2 * (1.f/DIN) - mu*mu;
        lmu[l2] = mu;
        lrs[l2] = rsqrtf(var + 1e-5f);
    }
    __syncthreads();
    for (int j = 0; j < 12; ++j) {
        int d = g + 16*j;
        float v = buf[l*193 + d];
        float tv = (v - lmu[l]) * lrs[l] * lng[d] + lnb[d];
        tv *= z_silu[((size_t)(b*DIN + d))*LL + l0 + l];
        buf[l*193 + d] = tv;
    }
    __syncthreads();
    int c0 = (t >> 4) * 6;
    float acc[6];
    #pragma unroll
    for (int cc = 0; cc < 6; ++cc) acc[cc] = 0.f;
    for (int d = 0; d < DIN; ++d) {
        float v = buf[l*193 + d];
        #pragma unroll
        for (int cc = 0; cc < 6; ++cc)
            acc[cc] += v * Wout[(c0 + cc)*DIN + d];
    }
    #pragma unroll
    for (int cc = 0; cc < 6; ++cc)
        out[((size_t)(b*LL + l0 + l))*CC + c0 + cc] = acc[cc];
}

// ---------------------------------------------------------------------------
extern "C" void kernel_launch(void* const* d_in, const int* in_sizes, int n_in,
                              void* d_out, int out_size, void* d_ws, size_t ws_size,
                              hipStream_t stream) {
    const float* x      = (const float*)d_in[0];
    const float* W_in   = (const float*)d_in[1];
    const float* conv_w = (const float*)d_in[2];
    const float* conv_b = (const float*)d_in[3];
    const float* xpw    = (const float*)d_in[4];
    const float* dt_w   = (const float*)d_in[5];
    const float* dt_b   = (const float*)d_in[6];
    const float* A_logs = (const float*)d_in[7];
    const float* Ds     = (const float*)d_in[8];
    const float* gate_w = (const float*)d_in[9];
    const float* gate_b = (const float*)d_in[10];
    const float* ln_g   = (const float*)d_in[11];
    const float* ln_b   = (const float*)d_in[12];
    const float* W_out  = (const float*)d_in[13];
    const int* scan_ids = (const int*)d_in[14];
    // d_in[15] = inv_ids, unused (scatter through scan_ids is the inverse)
    float* out = (float*)d_out;

    float* ws      = (float*)d_ws;
    float* xc_pre  = ws;                       // B*DIN*L        = 1,572,864
    float* z_silu  = xc_pre  + 1572864;        // B*DIN*L
    float* xconv   = z_silu  + 1572864;        // B*DIN*L
    float* delta   = xconv   + 1572864;        // B*K*DIN*L      = 6,291,456
    float* Bs      = delta   + 6291456;        // B*K*L*NST      = 524,288
    float* Cs      = Bs      + 524288;         // B*K*L*NST
    float* segA    = Cs      + 524288;         // B*K*SEG*DIN*NST = 393,216
    float* segB    = segA    + 393216;
    float* hinit   = segB    + 393216;
    float* y_dirs  = hinit   + 393216;         // B*K*DIN*L
    float* poolsum = y_dirs  + 6291456;        // B*DIN*K = 1536
    float* gate    = poolsum + 1536;           // B*DIN*K

    hipMemsetAsync(poolsum, 0, 1536*sizeof(float), stream);

    k_inproj<<<dim3(LL/64, BB), 256, 0, stream>>>(x, W_in, xc_pre, z_silu);
    k_conv<<<(BB*DIN*LL)/256, 256, 0, stream>>>(xc_pre, conv_w, conv_b, xconv);
    k_proj<<<dim3(LL/64, KK, BB), 256, 0, stream>>>(xconv, scan_ids, xpw, dt_w, dt_b,
                                                    Bs, Cs, delta);
    k_scan1<<<dim3(SEG, DIN/16, BB*KK), 256, 0, stream>>>(delta, xconv, Bs, scan_ids,
                                                          A_logs, segA, segB);
    k_scan2<<<(BB*KK*DIN*NST)/256, 256, 0, stream>>>(segA, segB, hinit);
    k_scan3<<<dim3(SEG, DIN/16, BB*KK), 256, 0, stream>>>(delta, xconv, Bs, Cs, scan_ids,
                                                          A_logs, Ds, hinit, y_dirs, poolsum);
    k_gate<<<(BB*DIN*KK)/256, 256, 0, stream>>>(poolsum, gate_w, gate_b, gate);
    k_final<<<dim3(LL/16, BB), 256, 0, stream>>>(y_dirs, gate, z_silu, ln_g, ln_b, W_out, out);
}

// Round 2
// 473.091 us; speedup vs baseline: 1.2292x; 1.2292x over previous
//
#include <hip/hip_runtime.h>
#include <math.h>

#define BB 2
#define CC 96
#define DIN 192
#define NST 16
#define RNK 6
#define KK 4
#define LL 4096
#define RTOT (RNK + 2*NST)   // 38

// Layouts (all scratch):
//   xc_pre, z_silu, xconv : [b][l][DIN]      (d contiguous)
//   delta                 : [bk][l_scan][DIN]
//   Bs, Cs                : [bk][l_scan][NST]
//   segA/segB/hinit       : [bk][seg][d][NST]
//   y_dirs                : [bk][l_spatial][DIN]

// ---------------------------------------------------------------------------
// K1: in_proj. Block = 64 l x 4 oc-groups; blockIdx.z picks oc half (xc vs z).
// Writes [l][d] via LDS transpose (16-float contiguous chunks per lane group).
__global__ __launch_bounds__(256) void k_inproj(const float* __restrict__ x,
        const float* __restrict__ W_in, float* __restrict__ xc_pre,
        float* __restrict__ z_silu) {
    __shared__ float lx[96*65];     // [c][l]
    __shared__ float ob[64*65];     // [l][j]  j = g*16+q
    int b = blockIdx.y, z = blockIdx.z;
    int l0 = blockIdx.x * 64;
    int t = threadIdx.x;
    for (int i = 0; i < 24; ++i) {
        int e = t + 256*i;               // 64*96 elems; c fast -> coalesced
        int l = e / 96, c = e % 96;
        lx[c*65 + l] = x[((size_t)(b*LL + l0 + l))*96 + c];
    }
    __syncthreads();
    int l = t & 63;
    int g = __builtin_amdgcn_readfirstlane(t >> 6);   // wave-uniform
    for (int ch = 0; ch < 3; ++ch) {
        int oc0 = z*192 + g*48 + ch*16;
        float acc[16];
        #pragma unroll
        for (int q = 0; q < 16; ++q) acc[q] = 0.f;
        for (int c = 0; c < 96; ++c) {
            float xv = lx[c*65 + l];
            #pragma unroll
            for (int q = 0; q < 16; ++q) acc[q] += xv * W_in[(oc0+q)*96 + c];
        }
        #pragma unroll
        for (int q = 0; q < 16; ++q) ob[l*65 + g*16 + q] = acc[q];
        __syncthreads();
        for (int i = 0; i < 16; ++i) {
            int e = t + 256*i;           // 64l x 64j
            int j = e & 63, ll = e >> 6;
            int oc = (j >> 4)*48 + ch*16 + (j & 15);   // local oc within half
            float v = ob[ll*65 + j];
            if (z == 0) {
                xc_pre[((size_t)(b*LL + l0 + ll))*DIN + oc] = v;
            } else {
                z_silu[((size_t)(b*LL + l0 + ll))*DIN + oc] = v / (1.f + __expf(-v));
            }
        }
        __syncthreads();
    }
}

// ---------------------------------------------------------------------------
// K2: depthwise 3x3 conv + bias + SiLU, [l][d] in/out, d fastest in tid.
__global__ __launch_bounds__(256) void k_conv(const float* __restrict__ xc,
        const float* __restrict__ cw, const float* __restrict__ cb,
        float* __restrict__ out) {
    int gid = blockIdx.x*256 + threadIdx.x;    // B*L*DIN total
    int d = gid % DIN;
    int r = gid / DIN;
    int l = r & 4095, b = r >> 12;
    int w = l & 63, h = l >> 6;
    float acc = cb[d];
    #pragma unroll
    for (int dh = -1; dh <= 1; ++dh) {
        int h2 = h + dh;
        bool okh = (h2 >= 0) && (h2 < 64);
        #pragma unroll
        for (int dw = -1; dw <= 1; ++dw) {
            int w2 = w + dw;
            if (okh && w2 >= 0 && w2 < 64)
                acc += xc[((size_t)(b*LL + h2*64 + w2))*DIN + d] * cw[d*9 + (dh+1)*3 + (dw+1)];
        }
    }
    out[((size_t)(b*LL + l))*DIN + d] = acc / (1.f + __expf(-acc));
}

// ---------------------------------------------------------------------------
// K3: x_proj + dt: gather xs tile (64 l), GEMV to dts/B/C, delta=softplus.
__global__ __launch_bounds__(256) void k_proj(const float* __restrict__ xconv,
        const int* __restrict__ scan_ids,
        const float* __restrict__ xpw, const float* __restrict__ dtw,
        const float* __restrict__ dtb,
        float* __restrict__ Bs, float* __restrict__ Cs, float* __restrict__ delta) {
    __shared__ float lxs[DIN*65];    // [d][l]
    __shared__ float lbc[64*33];     // [l][32]: 0..15 B, 16..31 C
    __shared__ float ldts[RNK*64];   // [r][l]
    __shared__ int lsid[64];
    int k = blockIdx.y, b = blockIdx.z;
    int l0 = blockIdx.x * 64;
    int t = threadIdx.x;
    if (t < 64) lsid[t] = scan_ids[k*LL + l0 + t];
    __syncthreads();
    for (int i = 0; i < 48; ++i) {
        int e = t + 256*i;           // d fast -> coalesced rows of xconv
        int d = e % DIN, l = e / DIN;
        lxs[d*65 + l] = xconv[((size_t)(b*LL + lsid[l]))*DIN + d];
    }
    __syncthreads();
    int l = t & 63;
    int rg = __builtin_amdgcn_readfirstlane(t >> 6);
    float acc[10];
    #pragma unroll
    for (int j = 0; j < 10; ++j) acc[j] = 0.f;
    for (int d = 0; d < DIN; ++d) {
        float xv = lxs[d*65 + l];
        #pragma unroll
        for (int j = 0; j < 10; ++j) {
            int r = rg + 4*j;
            if (r < RTOT) acc[j] += xv * xpw[(k*RTOT + r)*DIN + d];
        }
    }
    #pragma unroll
    for (int j = 0; j < 10; ++j) {
        int r = rg + 4*j;
        if (r < RTOT) {
            if (r < RNK) ldts[r*64 + l] = acc[j];
            else         lbc[l*33 + (r - RNK)] = acc[j];
        }
    }
    __syncthreads();
    // write Bs/Cs coalesced
    size_t rowb = ((size_t)((b*KK + k)*LL + l0))*NST;
    for (int i = 0; i < 4; ++i) {
        int e = t + 256*i;           // 1024 = 64l x 16n
        int n = e & 15, ll = e >> 4;
        Bs[rowb + ll*NST + n] = lbc[ll*33 + n];
        Cs[rowb + ll*NST + n] = lbc[ll*33 + 16 + n];
    }
    // delta: d fast -> coalesced [l][d] writes
    for (int i = 0; i < 48; ++i) {
        int e = t + 256*i;
        int d = e % DIN, ll = e / DIN;
        float a = dtb[k*DIN + d];
        #pragma unroll
        for (int r = 0; r < RNK; ++r)
            a += ldts[r*64 + ll] * dtw[(k*DIN + d)*RNK + r];
        float sp = (a > 15.f) ? a : log1pf(__expf(a));
        delta[((size_t)((b*KK + k)*LL + l0 + ll))*DIN + d] = sp;
    }
}

// ---------------------------------------------------------------------------
// K4: scan pass 1 — per-segment (prod e, partial h), one channel per lane,
// 16 states in registers. No LDS (except tiny lsid). All loads coalesced.
__global__ __launch_bounds__(192) void k_scan1(const float* __restrict__ delta,
        const float* __restrict__ xconv, const float* __restrict__ Bs,
        const int* __restrict__ scan_ids, const float* __restrict__ A_logs,
        float* __restrict__ segA, float* __restrict__ segB, int SL) {
    __shared__ int lsid[256];
    int seg = blockIdx.x, bk = blockIdx.y;
    int b = bk >> 2, k = bk & 3;
    int d = threadIdx.x;
    int l0 = seg * SL;
    for (int i = threadIdx.x; i < SL; i += 192) lsid[i] = scan_ids[k*LL + l0 + i];
    __syncthreads();
    float Av[16];
    {
        const float4* ap = (const float4*)(A_logs + (k*DIN + d)*NST);
        #pragma unroll
        for (int q = 0; q < 4; ++q) {
            float4 v = ap[q];
            Av[4*q+0] = -__expf(v.x); Av[4*q+1] = -__expf(v.y);
            Av[4*q+2] = -__expf(v.z); Av[4*q+3] = -__expf(v.w);
        }
    }
    float a[16], h[16];
    #pragma unroll
    for (int n = 0; n < 16; ++n) { a[n] = 1.f; h[n] = 0.f; }
    const float* dp = delta + ((size_t)bk*LL + l0)*DIN + d;
    const float4* bq = (const float4*)(Bs + ((size_t)bk*LL + l0)*NST);
    for (int li = 0; li < SL; ++li) {
        float dv = dp[(size_t)li*DIN];
        float xv = xconv[((size_t)(b*LL + lsid[li]))*DIN + d];
        float dxv = dv * xv;
        float bb[16];
        #pragma unroll
        for (int q = 0; q < 4; ++q) {
            float4 v = bq[li*4 + q];
            bb[4*q+0] = v.x; bb[4*q+1] = v.y; bb[4*q+2] = v.z; bb[4*q+3] = v.w;
        }
        #pragma unroll
        for (int n = 0; n < 16; ++n) {
            float e = __expf(dv * Av[n]);
            a[n] *= e;
            h[n] = e*h[n] + dxv*bb[n];
        }
    }
    float4* sa = (float4*)(segA + (((size_t)bk*gridDim.x + seg)*DIN + d)*NST);
    float4* sb = (float4*)(segB + (((size_t)bk*gridDim.x + seg)*DIN + d)*NST);
    #pragma unroll
    for (int q = 0; q < 4; ++q) {
        sa[q] = make_float4(a[4*q], a[4*q+1], a[4*q+2], a[4*q+3]);
        sb[q] = make_float4(h[4*q], h[4*q+1], h[4*q+2], h[4*q+3]);
    }
}

// ---------------------------------------------------------------------------
// K5: compose segment carries -> initial state per segment
__global__ __launch_bounds__(256) void k_scan2(const float* __restrict__ segA,
        const float* __restrict__ segB, float* __restrict__ hinit, int SEGC) {
    int idx = blockIdx.x*256 + threadIdx.x;     // (bk, d*NST+n)
    if (idx >= BB*KK*DIN*NST) return;
    int bk = idx / (DIN*NST);
    int dn = idx % (DIN*NST);
    float h = 0.f;
    for (int s = 0; s < SEGC; ++s) {
        size_t o = ((size_t)(bk*SEGC + s))*(DIN*NST) + dn;
        hinit[o] = h;
        h = segA[o]*h + segB[o];
    }
}

// ---------------------------------------------------------------------------
// K6: scan pass 3 — replay with h0, y = sum_n h*C + xs*D, coalesced scatter
// to spatial [l][d], pool accumulation in-register.
__global__ __launch_bounds__(192) void k_scan3(const float* __restrict__ delta,
        const float* __restrict__ xconv, const float* __restrict__ Bs,
        const float* __restrict__ Cs,
        const int* __restrict__ scan_ids, const float* __restrict__ A_logs,
        const float* __restrict__ Ds, const float* __restrict__ hinit,
        float* __restrict__ y_dirs, float* __restrict__ poolsum, int SL) {
    __shared__ int lsid[256];
    int seg = blockIdx.x, bk = blockIdx.y;
    int b = bk >> 2, k = bk & 3;
    int d = threadIdx.x;
    int l0 = seg * SL;
    for (int i = threadIdx.x; i < SL; i += 192) lsid[i] = scan_ids[k*LL + l0 + i];
    __syncthreads();
    float Av[16];
    {
        const float4* ap = (const float4*)(A_logs + (k*DIN + d)*NST);
        #pragma unroll
        for (int q = 0; q < 4; ++q) {
            float4 v = ap[q];
            Av[4*q+0] = -__expf(v.x); Av[4*q+1] = -__expf(v.y);
            Av[4*q+2] = -__expf(v.z); Av[4*q+3] = -__expf(v.w);
        }
    }
    float Dv = Ds[k*DIN + d];
    float h[16];
    {
        const float4* hp = (const float4*)(hinit + (((size_t)bk*gridDim.x + seg)*DIN + d)*NST);
        #pragma unroll
        for (int q = 0; q < 4; ++q) {
            float4 v = hp[q];
            h[4*q+0] = v.x; h[4*q+1] = v.y; h[4*q+2] = v.z; h[4*q+3] = v.w;
        }
    }
    const float* dp = delta + ((size_t)bk*LL + l0)*DIN + d;
    const float4* bq = (const float4*)(Bs + ((size_t)bk*LL + l0)*NST);
    const float4* cq = (const float4*)(Cs + ((size_t)bk*LL + l0)*NST);
    float pool = 0.f;
    for (int li = 0; li < SL; ++li) {
        float dv = dp[(size_t)li*DIN];
        int l = lsid[li];
        float xv = xconv[((size_t)(b*LL + l))*DIN + d];
        float dxv = dv * xv;
        float bb[16], cc[16];
        #pragma unroll
        for (int q = 0; q < 4; ++q) {
            float4 v = bq[li*4 + q];
            bb[4*q+0] = v.x; bb[4*q+1] = v.y; bb[4*q+2] = v.z; bb[4*q+3] = v.w;
            float4 u = cq[li*4 + q];
            cc[4*q+0] = u.x; cc[4*q+1] = u.y; cc[4*q+2] = u.z; cc[4*q+3] = u.w;
        }
        float y = 0.f;
        #pragma unroll
        for (int n = 0; n < 16; ++n) {
            float e = __expf(dv * Av[n]);
            h[n] = e*h[n] + dxv*bb[n];
            y += h[n]*cc[n];
        }
        y += xv * Dv;
        y_dirs[((size_t)(bk*LL + l))*DIN + d] = y;
        pool += y;
    }
    atomicAdd(&poolsum[(b*DIN + d)*KK + k], pool);
}

// ---------------------------------------------------------------------------
// K7: gate
__global__ void k_gate(const float* __restrict__ poolsum, const float* __restrict__ gw,
        const float* __restrict__ gb, float* __restrict__ gate) {
    int idx = blockIdx.x*256 + threadIdx.x;
    int o = idx & 3;
    int bd = idx >> 2;
    int d = bd % DIN;
    float acc = gb[d*KK + o];
    #pragma unroll
    for (int i = 0; i < KK; ++i)
        acc += (poolsum[bd*KK + i] * (1.f/LL)) * gw[(d*KK + o)*KK + i];
    gate[idx] = 1.f/(1.f + __expf(-acc));
}

// ---------------------------------------------------------------------------
// K8: y = sum_k gate*y_dirs ; LN ; * silu(z) ; @ W_out^T. [l][d] inputs.
__global__ __launch_bounds__(256) void k_final(const float* __restrict__ y_dirs,
        const float* __restrict__ gate, const float* __restrict__ z_silu,
        const float* __restrict__ lng, const float* __restrict__ lnb,
        const float* __restrict__ Wout, float* __restrict__ out) {
    __shared__ float buf[16*193];
    __shared__ float lmu[16], lrs[16];
    int b = blockIdx.y;
    int l0 = blockIdx.x * 16;
    int t = threadIdx.x;
    for (int i = 0; i < 12; ++i) {
        int e = t + 256*i;               // 3072 = 16l x 192d, d fast
        int d = e % DIN, l = e / DIN;
        float acc = 0.f;
        #pragma unroll
        for (int k = 0; k < KK; ++k)
            acc += y_dirs[((size_t)((b*KK + k)*LL + l0 + l))*DIN + d] * gate[(b*DIN + d)*KK + k];
        buf[l*193 + d] = acc;
    }
    __syncthreads();
    int l2 = t >> 4, q = t & 15;
    float s = 0.f, s2 = 0.f;
    for (int i = 0; i < 12; ++i) {
        float v = buf[l2*193 + q + 16*i];
        s += v; s2 += v*v;
    }
    s += __shfl_xor(s, 1);  s2 += __shfl_xor(s2, 1);
    s += __shfl_xor(s, 2);  s2 += __shfl_xor(s2, 2);
    s += __shfl_xor(s, 4);  s2 += __shfl_xor(s2, 4);
    s += __shfl_xor(s, 8);  s2 += __shfl_xor(s2, 8);
    if (q == 0) {
        float mu = s * (1.f/DIN);
        float var = s2 * (1.f/DIN) - mu*mu;
        lmu[l2] = mu;
        lrs[l2] = rsqrtf(var + 1e-5f);
    }
    __syncthreads();
    for (int i = 0; i < 12; ++i) {
        int e = t + 256*i;
        int d = e % DIN, l = e / DIN;
        float v = buf[l*193 + d];
        float tv = (v - lmu[l]) * lrs[l] * lng[d] + lnb[d];
        tv *= z_silu[((size_t)(b*LL + l0 + l))*DIN + d];
        buf[l*193 + d] = tv;
    }
    __syncthreads();
    int l = t & 15;
    int c0 = (t >> 4) * 6;
    float acc[6];
    #pragma unroll
    for (int cc = 0; cc < 6; ++cc) acc[cc] = 0.f;
    for (int d = 0; d < DIN; ++d) {
        float v = buf[l*193 + d];
        #pragma unroll
        for (int cc = 0; cc < 6; ++cc)
            acc[cc] += v * Wout[(c0 + cc)*DIN + d];
    }
    #pragma unroll
    for (int cc = 0; cc < 6; ++cc)
        out[((size_t)(b*LL + l0 + l))*CC + c0 + cc] = acc[cc];
}

// ---------------------------------------------------------------------------
extern "C" void kernel_launch(void* const* d_in, const int* in_sizes, int n_in,
                              void* d_out, int out_size, void* d_ws, size_t ws_size,
                              hipStream_t stream) {
    const float* x      = (const float*)d_in[0];
    const float* W_in   = (const float*)d_in[1];
    const float* conv_w = (const float*)d_in[2];
    const float* conv_b = (const float*)d_in[3];
    const float* xpw    = (const float*)d_in[4];
    const float* dt_w   = (const float*)d_in[5];
    const float* dt_b   = (const float*)d_in[6];
    const float* A_logs = (const float*)d_in[7];
    const float* Ds     = (const float*)d_in[8];
    const float* gate_w = (const float*)d_in[9];
    const float* gate_b = (const float*)d_in[10];
    const float* ln_g   = (const float*)d_in[11];
    const float* ln_b   = (const float*)d_in[12];
    const float* W_out  = (const float*)d_in[13];
    const int* scan_ids = (const int*)d_in[14];
    float* out = (float*)d_out;

    // Pick segment count to fit ws_size (SEGC=16 matches the proven 78 MB).
    const size_t baseF = 3ull*1572864 + 6291456 + 2ull*524288 + 6291456 + 2ull*1536;
    int SEGC = 16;
    if ((baseF + 3ull*128*24576)*4 <= ws_size) SEGC = 128;
    else if ((baseF + 3ull*64*24576)*4 <= ws_size) SEGC = 64;
    else if ((baseF + 3ull*32*24576)*4 <= ws_size) SEGC = 32;
    int SL = LL / SEGC;
    size_t segF = (size_t)SEGC * 24576;   // BB*KK*DIN*NST * SEGC

    float* ws      = (float*)d_ws;
    float* xc_pre  = ws;
    float* z_silu  = xc_pre  + 1572864;
    float* xconv   = z_silu  + 1572864;
    float* delta   = xconv   + 1572864;
    float* Bs      = delta   + 6291456;
    float* Cs      = Bs      + 524288;
    float* segA    = Cs      + 524288;
    float* segB    = segA    + segF;
    float* hinit   = segB    + segF;
    float* y_dirs  = hinit   + segF;
    float* poolsum = y_dirs  + 6291456;
    float* gate    = poolsum + 1536;

    hipMemsetAsync(poolsum, 0, 1536*sizeof(float), stream);

    k_inproj<<<dim3(LL/64, BB, 2), 256, 0, stream>>>(x, W_in, xc_pre, z_silu);
    k_conv<<<(BB*DIN*LL)/256, 256, 0, stream>>>(xc_pre, conv_w, conv_b, xconv);
    k_proj<<<dim3(LL/64, KK, BB), 256, 0, stream>>>(xconv, scan_ids, xpw, dt_w, dt_b,
                                                    Bs, Cs, delta);
    k_scan1<<<dim3(SEGC, BB*KK), 192, 0, stream>>>(delta, xconv, Bs, scan_ids,
                                                   A_logs, segA, segB, SL);
    k_scan2<<<(BB*KK*DIN*NST + 255)/256, 256, 0, stream>>>(segA, segB, hinit, SEGC);
    k_scan3<<<dim3(SEGC, BB*KK), 192, 0, stream>>>(delta, xconv, Bs, Cs, scan_ids,
                                                   A_logs, Ds, hinit, y_dirs, poolsum, SL);
    k_gate<<<(BB*DIN*KK)/256, 256, 0, stream>>>(poolsum, gate_w, gate_b, gate);
    k_final<<<dim3(LL/16, BB), 256, 0, stream>>>(y_dirs, gate, z_silu, ln_g, ln_b, W_out, out);
}

// Round 3
// 384.654 us; speedup vs baseline: 1.5119x; 1.2299x over previous
//
#include <hip/hip_runtime.h>
#include <math.h>

#define BB 2
#define CC 96
#define DIN 192
#define NST 16
#define RNK 6
#define KK 4
#define LL 4096
#define RTOT (RNK + 2*NST)   // 38

// Layouts (all scratch):
//   xc_pre (aliases y_dirs), z_silu, xconv : [b][l][DIN]
//   delta  : [bk][l_scan][DIN]
//   Bs, Cs : [bk][l_scan][NST]
//   segA/segB/hinit : [bk][seg][d][NST]
//   y_dirs : [bk][l_spatial][DIN]

// ---------------------------------------------------------------------------
// K1: in_proj. Block = 64 l x 4 oc-groups; blockIdx.z picks oc half (xc vs z).
__global__ __launch_bounds__(256) void k_inproj(const float* __restrict__ x,
        const float* __restrict__ W_in, float* __restrict__ xc_pre,
        float* __restrict__ z_silu) {
    __shared__ float lx[96*65];     // [c][l]
    __shared__ float ob[64*65];     // [l][j]
    int b = blockIdx.y, z = blockIdx.z;
    int l0 = blockIdx.x * 64;
    int t = threadIdx.x;
    for (int i = 0; i < 24; ++i) {
        int e = t + 256*i;
        int l = e / 96, c = e % 96;
        lx[c*65 + l] = x[((size_t)(b*LL + l0 + l))*96 + c];
    }
    __syncthreads();
    int l = t & 63;
    int g = __builtin_amdgcn_readfirstlane(t >> 6);
    for (int ch = 0; ch < 3; ++ch) {
        int oc0 = z*192 + g*48 + ch*16;
        float acc[16];
        #pragma unroll
        for (int q = 0; q < 16; ++q) acc[q] = 0.f;
        for (int c = 0; c < 96; ++c) {
            float xv = lx[c*65 + l];
            #pragma unroll
            for (int q = 0; q < 16; ++q) acc[q] += xv * W_in[(oc0+q)*96 + c];
        }
        #pragma unroll
        for (int q = 0; q < 16; ++q) ob[l*65 + g*16 + q] = acc[q];
        __syncthreads();
        for (int i = 0; i < 16; ++i) {
            int e = t + 256*i;
            int j = e & 63, ll = e >> 6;
            int oc = (j >> 4)*48 + ch*16 + (j & 15);
            float v = ob[ll*65 + j];
            if (z == 0) {
                xc_pre[((size_t)(b*LL + l0 + ll))*DIN + oc] = v;
            } else {
                z_silu[((size_t)(b*LL + l0 + ll))*DIN + oc] = v / (1.f + __expf(-v));
            }
        }
        __syncthreads();
    }
}

// ---------------------------------------------------------------------------
// K2: depthwise 3x3 conv + bias + SiLU, [l][d] in/out.
__global__ __launch_bounds__(256) void k_conv(const float* __restrict__ xc,
        const float* __restrict__ cw, const float* __restrict__ cb,
        float* __restrict__ out) {
    int gid = blockIdx.x*256 + threadIdx.x;
    int d = gid % DIN;
    int r = gid / DIN;
    int l = r & 4095, b = r >> 12;
    int w = l & 63, h = l >> 6;
    float acc = cb[d];
    #pragma unroll
    for (int dh = -1; dh <= 1; ++dh) {
        int h2 = h + dh;
        bool okh = (h2 >= 0) && (h2 < 64);
        #pragma unroll
        for (int dw = -1; dw <= 1; ++dw) {
            int w2 = w + dw;
            if (okh && w2 >= 0 && w2 < 64)
                acc += xc[((size_t)(b*LL + h2*64 + w2))*DIN + d] * cw[d*9 + (dh+1)*3 + (dw+1)];
        }
    }
    out[((size_t)(b*LL + l))*DIN + d] = acc / (1.f + __expf(-acc));
}

// ---------------------------------------------------------------------------
// K3: x_proj + dt. 512 threads: lanes = 64 l, 8 wave-uniform row groups.
// d-loop unrolled x4 for LDS-latency hiding; fast softplus.
__global__ __launch_bounds__(512) void k_proj(const float* __restrict__ xconv,
        const int* __restrict__ scan_ids,
        const float* __restrict__ xpw, const float* __restrict__ dtw,
        const float* __restrict__ dtb,
        float* __restrict__ Bs, float* __restrict__ Cs, float* __restrict__ delta) {
    __shared__ float lxs[DIN*65];    // [d][l]
    __shared__ float lbc[64*33];     // [l][32]: 0..15 B, 16..31 C
    __shared__ float ldts[RNK*64];   // [r][l]
    __shared__ int lsid[64];
    int k = blockIdx.y, b = blockIdx.z;
    int l0 = blockIdx.x * 64;
    int t = threadIdx.x;
    if (t < 64) lsid[t] = scan_ids[k*LL + l0 + t];
    __syncthreads();
    for (int i = 0; i < 24; ++i) {
        int e = t + 512*i;           // 12288 = 64l x 192d, d fast -> coalesced
        int d = e % DIN, l = e / DIN;
        lxs[d*65 + l] = xconv[((size_t)(b*LL + lsid[l]))*DIN + d];
    }
    __syncthreads();
    int l = t & 63;
    int rg = __builtin_amdgcn_readfirstlane(t >> 6);    // 0..7, wave-uniform
    float acc[5];
    #pragma unroll
    for (int j = 0; j < 5; ++j) acc[j] = 0.f;
    const float* wp = xpw + (size_t)k*RTOT*DIN;
    for (int d = 0; d < DIN; d += 4) {
        float x0 = lxs[(d+0)*65 + l];
        float x1 = lxs[(d+1)*65 + l];
        float x2 = lxs[(d+2)*65 + l];
        float x3 = lxs[(d+3)*65 + l];
        #pragma unroll
        for (int j = 0; j < 5; ++j) {
            int r = rg + 8*j;
            if (r < RTOT) {
                const float* w = wp + r*DIN + d;
                acc[j] += x0*w[0] + x1*w[1] + x2*w[2] + x3*w[3];
            }
        }
    }
    #pragma unroll
    for (int j = 0; j < 5; ++j) {
        int r = rg + 8*j;
        if (r < RTOT) {
            if (r < RNK) ldts[r*64 + l] = acc[j];
            else         lbc[l*33 + (r - RNK)] = acc[j];
        }
    }
    __syncthreads();
    size_t rowb = ((size_t)((b*KK + k)*LL + l0))*NST;
    for (int i = 0; i < 2; ++i) {
        int e = t + 512*i;           // 1024 = 64l x 16n
        int n = e & 15, ll = e >> 4;
        Bs[rowb + ll*NST + n] = lbc[ll*33 + n];
        Cs[rowb + ll*NST + n] = lbc[ll*33 + 16 + n];
    }
    for (int i = 0; i < 24; ++i) {
        int e = t + 512*i;
        int d = e % DIN, ll = e / DIN;
        float a = dtb[k*DIN + d];
        #pragma unroll
        for (int r = 0; r < RNK; ++r)
            a += ldts[r*64 + ll] * dtw[(k*DIN + d)*RNK + r];
        float sp = fmaxf(a, 0.f) + __logf(1.f + __expf(-fabsf(a)));
        delta[((size_t)((b*KK + k)*LL + l0 + ll))*DIN + d] = sp;
    }
}

// ---------------------------------------------------------------------------
// K4: scan pass 1 — per-segment (prod e, partial h), one channel per lane.
__global__ __launch_bounds__(192) void k_scan1(const float* __restrict__ delta,
        const float* __restrict__ xconv, const float* __restrict__ Bs,
        const int* __restrict__ scan_ids, const float* __restrict__ A_logs,
        float* __restrict__ segA, float* __restrict__ segB, int SL) {
    __shared__ int lsid[256];
    int seg = blockIdx.x, bk = blockIdx.y;
    int b = bk >> 2, k = bk & 3;
    int d = threadIdx.x;
    int l0 = seg * SL;
    for (int i = threadIdx.x; i < SL; i += 192) lsid[i] = scan_ids[k*LL + l0 + i];
    __syncthreads();
    float Av[16];
    {
        const float4* ap = (const float4*)(A_logs + (k*DIN + d)*NST);
        #pragma unroll
        for (int q = 0; q < 4; ++q) {
            float4 v = ap[q];
            Av[4*q+0] = -__expf(v.x); Av[4*q+1] = -__expf(v.y);
            Av[4*q+2] = -__expf(v.z); Av[4*q+3] = -__expf(v.w);
        }
    }
    float a[16], h[16];
    #pragma unroll
    for (int n = 0; n < 16; ++n) { a[n] = 1.f; h[n] = 0.f; }
    const float* dp = delta + ((size_t)bk*LL + l0)*DIN + d;
    const float4* bq = (const float4*)(Bs + ((size_t)bk*LL + l0)*NST);
    for (int li = 0; li < SL; ++li) {
        float dv = dp[(size_t)li*DIN];
        float xv = xconv[((size_t)(b*LL + lsid[li]))*DIN + d];
        float dxv = dv * xv;
        float bb[16];
        #pragma unroll
        for (int q = 0; q < 4; ++q) {
            float4 v = bq[li*4 + q];
            bb[4*q+0] = v.x; bb[4*q+1] = v.y; bb[4*q+2] = v.z; bb[4*q+3] = v.w;
        }
        #pragma unroll
        for (int n = 0; n < 16; ++n) {
            float e = __expf(dv * Av[n]);
            a[n] *= e;
            h[n] = e*h[n] + dxv*bb[n];
        }
    }
    float4* sa = (float4*)(segA + (((size_t)bk*gridDim.x + seg)*DIN + d)*NST);
    float4* sb = (float4*)(segB + (((size_t)bk*gridDim.x + seg)*DIN + d)*NST);
    #pragma unroll
    for (int q = 0; q < 4; ++q) {
        sa[q] = make_float4(a[4*q], a[4*q+1], a[4*q+2], a[4*q+3]);
        sb[q] = make_float4(h[4*q], h[4*q+1], h[4*q+2], h[4*q+3]);
    }
}

// ---------------------------------------------------------------------------
// K5: compose segment carries -> initial state per segment
__global__ __launch_bounds__(256) void k_scan2(const float* __restrict__ segA,
        const float* __restrict__ segB, float* __restrict__ hinit, int SEGC) {
    int idx = blockIdx.x*256 + threadIdx.x;
    if (idx >= BB*KK*DIN*NST) return;
    int bk = idx / (DIN*NST);
    int dn = idx % (DIN*NST);
    float h = 0.f;
    for (int s = 0; s < SEGC; ++s) {
        size_t o = ((size_t)(bk*SEGC + s))*(DIN*NST) + dn;
        hinit[o] = h;
        h = segA[o]*h + segB[o];
    }
}

// ---------------------------------------------------------------------------
// K6: scan pass 3 — replay with h0, y = sum_n h*C + xs*D, coalesced scatter.
__global__ __launch_bounds__(192) void k_scan3(const float* __restrict__ delta,
        const float* __restrict__ xconv, const float* __restrict__ Bs,
        const float* __restrict__ Cs,
        const int* __restrict__ scan_ids, const float* __restrict__ A_logs,
        const float* __restrict__ Ds, const float* __restrict__ hinit,
        float* __restrict__ y_dirs, float* __restrict__ poolsum, int SL) {
    __shared__ int lsid[256];
    int seg = blockIdx.x, bk = blockIdx.y;
    int b = bk >> 2, k = bk & 3;
    int d = threadIdx.x;
    int l0 = seg * SL;
    for (int i = threadIdx.x; i < SL; i += 192) lsid[i] = scan_ids[k*LL + l0 + i];
    __syncthreads();
    float Av[16];
    {
        const float4* ap = (const float4*)(A_logs + (k*DIN + d)*NST);
        #pragma unroll
        for (int q = 0; q < 4; ++q) {
            float4 v = ap[q];
            Av[4*q+0] = -__expf(v.x); Av[4*q+1] = -__expf(v.y);
            Av[4*q+2] = -__expf(v.z); Av[4*q+3] = -__expf(v.w);
        }
    }
    float Dv = Ds[k*DIN + d];
    float h[16];
    {
        const float4* hp = (const float4*)(hinit + (((size_t)bk*gridDim.x + seg)*DIN + d)*NST);
        #pragma unroll
        for (int q = 0; q < 4; ++q) {
            float4 v = hp[q];
            h[4*q+0] = v.x; h[4*q+1] = v.y; h[4*q+2] = v.z; h[4*q+3] = v.w;
        }
    }
    const float* dp = delta + ((size_t)bk*LL + l0)*DIN + d;
    const float4* bq = (const float4*)(Bs + ((size_t)bk*LL + l0)*NST);
    const float4* cq = (const float4*)(Cs + ((size_t)bk*LL + l0)*NST);
    float pool = 0.f;
    for (int li = 0; li < SL; ++li) {
        float dv = dp[(size_t)li*DIN];
        int l = lsid[li];
        float xv = xconv[((size_t)(b*LL + l))*DIN + d];
        float dxv = dv * xv;
        float bb[16], cc[16];
        #pragma unroll
        for (int q = 0; q < 4; ++q) {
            float4 v = bq[li*4 + q];
            bb[4*q+0] = v.x; bb[4*q+1] = v.y; bb[4*q+2] = v.z; bb[4*q+3] = v.w;
            float4 u = cq[li*4 + q];
            cc[4*q+0] = u.x; cc[4*q+1] = u.y; cc[4*q+2] = u.z; cc[4*q+3] = u.w;
        }
        float y = 0.f;
        #pragma unroll
        for (int n = 0; n < 16; ++n) {
            float e = __expf(dv * Av[n]);
            h[n] = e*h[n] + dxv*bb[n];
            y += h[n]*cc[n];
        }
        y += xv * Dv;
        y_dirs[((size_t)(bk*LL + l))*DIN + d] = y;
        pool += y;
    }
    atomicAdd(&poolsum[(b*DIN + d)*KK + k], pool);
}

// ---------------------------------------------------------------------------
// K7: gate
__global__ void k_gate(const float* __restrict__ poolsum, const float* __restrict__ gw,
        const float* __restrict__ gb, float* __restrict__ gate) {
    int idx = blockIdx.x*256 + threadIdx.x;
    int o = idx & 3;
    int bd = idx >> 2;
    int d = bd % DIN;
    float acc = gb[d*KK + o];
    #pragma unroll
    for (int i = 0; i < KK; ++i)
        acc += (poolsum[bd*KK + i] * (1.f/LL)) * gw[(d*KK + o)*KK + i];
    gate[idx] = 1.f/(1.f + __expf(-acc));
}

// ---------------------------------------------------------------------------
// K8: y = sum_k gate*y_dirs ; LN ; * silu(z) ; @ W_out^T.
__global__ __launch_bounds__(256) void k_final(const float* __restrict__ y_dirs,
        const float* __restrict__ gate, const float* __restrict__ z_silu,
        const float* __restrict__ lng, const float* __restrict__ lnb,
        const float* __restrict__ Wout, float* __restrict__ out) {
    __shared__ float buf[16*193];
    __shared__ float lmu[16], lrs[16];
    int b = blockIdx.y;
    int l0 = blockIdx.x * 16;
    int t = threadIdx.x;
    for (int i = 0; i < 12; ++i) {
        int e = t + 256*i;
        int d = e % DIN, l = e / DIN;
        float acc = 0.f;
        #pragma unroll
        for (int k = 0; k < KK; ++k)
            acc += y_dirs[((size_t)((b*KK + k)*LL + l0 + l))*DIN + d] * gate[(b*DIN + d)*KK + k];
        buf[l*193 + d] = acc;
    }
    __syncthreads();
    int l2 = t >> 4, q = t & 15;
    float s = 0.f, s2 = 0.f;
    for (int i = 0; i < 12; ++i) {
        float v = buf[l2*193 + q + 16*i];
        s += v; s2 += v*v;
    }
    s += __shfl_xor(s, 1);  s2 += __shfl_xor(s2, 1);
    s += __shfl_xor(s, 2);  s2 += __shfl_xor(s2, 2);
    s += __shfl_xor(s, 4);  s2 += __shfl_xor(s2, 4);
    s += __shfl_xor(s, 8);  s2 += __shfl_xor(s2, 8);
    if (q == 0) {
        float mu = s * (1.f/DIN);
        float var = s2 * (1.f/DIN) - mu*mu;
        lmu[l2] = mu;
        lrs[l2] = rsqrtf(var + 1e-5f);
    }
    __syncthreads();
    for (int i = 0; i < 12; ++i) {
        int e = t + 256*i;
        int d = e % DIN, l = e / DIN;
        float v = buf[l*193 + d];
        float tv = (v - lmu[l]) * lrs[l] * lng[d] + lnb[d];
        tv *= z_silu[((size_t)(b*LL + l0 + l))*DIN + d];
        buf[l*193 + d] = tv;
    }
    __syncthreads();
    int l = t & 15;
    int c0 = (t >> 4) * 6;
    float acc[6];
    #pragma unroll
    for (int cc = 0; cc < 6; ++cc) acc[cc] = 0.f;
    for (int d = 0; d < DIN; ++d) {
        float v = buf[l*193 + d];
        #pragma unroll
        for (int cc = 0; cc < 6; ++cc)
            acc[cc] += v * Wout[(c0 + cc)*DIN + d];
    }
    #pragma unroll
    for (int cc = 0; cc < 6; ++cc)
        out[((size_t)(b*LL + l0 + l))*CC + c0 + cc] = acc[cc];
}

// ---------------------------------------------------------------------------
extern "C" void kernel_launch(void* const* d_in, const int* in_sizes, int n_in,
                              void* d_out, int out_size, void* d_ws, size_t ws_size,
                              hipStream_t stream) {
    const float* x      = (const float*)d_in[0];
    const float* W_in   = (const float*)d_in[1];
    const float* conv_w = (const float*)d_in[2];
    const float* conv_b = (const float*)d_in[3];
    const float* xpw    = (const float*)d_in[4];
    const float* dt_w   = (const float*)d_in[5];
    const float* dt_b   = (const float*)d_in[6];
    const float* A_logs = (const float*)d_in[7];
    const float* Ds     = (const float*)d_in[8];
    const float* gate_w = (const float*)d_in[9];
    const float* gate_b = (const float*)d_in[10];
    const float* ln_g   = (const float*)d_in[11];
    const float* ln_b   = (const float*)d_in[12];
    const float* W_out  = (const float*)d_in[13];
    const int* scan_ids = (const int*)d_in[14];
    float* out = (float*)d_out;

    // Scratch layout with xc_pre aliased into y_dirs (xc_pre dead after k_conv,
    // y_dirs first written in k_scan3). Segment buffers last, sized at runtime.
    const size_t baseF = 6291456ull /*y_dirs|xc_pre*/ + 2ull*1572864 /*z,xconv*/
                       + 6291456ull /*delta*/ + 2ull*524288 /*Bs,Cs*/ + 3072;
    int SEGC = 16;
    if ((baseF + 3ull*128*24576)*4 <= ws_size) SEGC = 128;
    else if ((baseF + 3ull*64*24576)*4 <= ws_size) SEGC = 64;
    else if ((baseF + 3ull*32*24576)*4 <= ws_size) SEGC = 32;
    int SL = LL / SEGC;
    size_t segF = (size_t)SEGC * 24576;   // BB*KK*DIN*NST per buffer

    float* ws      = (float*)d_ws;
    float* y_dirs  = ws;                       // 6291456
    float* xc_pre  = ws;                       // alias
    float* z_silu  = y_dirs  + 6291456;
    float* xconv   = z_silu  + 1572864;
    float* delta   = xconv   + 1572864;
    float* Bs      = delta   + 6291456;
    float* Cs      = Bs      + 524288;
    float* poolsum = Cs      + 524288;
    float* gate    = poolsum + 1536;
    float* segA    = gate    + 1536;
    float* segB    = segA    + segF;
    float* hinit   = segB    + segF;

    hipMemsetAsync(poolsum, 0, 1536*sizeof(float), stream);

    k_inproj<<<dim3(LL/64, BB, 2), 256, 0, stream>>>(x, W_in, xc_pre, z_silu);
    k_conv<<<(BB*DIN*LL)/256, 256, 0, stream>>>(xc_pre, conv_w, conv_b, xconv);
    k_proj<<<dim3(LL/64, KK, BB), 512, 0, stream>>>(xconv, scan_ids, xpw, dt_w, dt_b,
                                                    Bs, Cs, delta);
    k_scan1<<<dim3(SEGC, BB*KK), 192, 0, stream>>>(delta, xconv, Bs, scan_ids,
                                                   A_logs, segA, segB, SL);
    k_scan2<<<(BB*KK*DIN*NST + 255)/256, 256, 0, stream>>>(segA, segB, hinit, SEGC);
    k_scan3<<<dim3(SEGC, BB*KK), 192, 0, stream>>>(delta, xconv, Bs, Cs, scan_ids,
                                                   A_logs, Ds, hinit, y_dirs, poolsum, SL);
    k_gate<<<(BB*DIN*KK)/256, 256, 0, stream>>>(poolsum, gate_w, gate_b, gate);
    k_final<<<dim3(LL/16, BB), 256, 0, stream>>>(y_dirs, gate, z_silu, ln_g, ln_b, W_out, out);
}

// Round 4
// 319.469 us; speedup vs baseline: 1.8204x; 1.2040x over previous
//
#include <hip/hip_runtime.h>
#include <math.h>

#define BB 2
#define CC 96
#define DIN 192
#define NST 16
#define RNK 6
#define KK 4
#define LL 4096
#define RTOT (RNK + 2*NST)   // 38

// Layouts (all scratch):
//   xc_pre (aliases y_dirs), z_silu, xconv : [b][l][DIN]
//   delta  : [bk][l_scan][DIN]
//   Bs, Cs : [bk][l_scan][NST]
//   segA/segB/hinit : [bk][seg][d][NST]
//   y_dirs : [bk][l_spatial][DIN]

// ---------------------------------------------------------------------------
// K1: in_proj with weights staged in LDS (kills the s_load/ds_read lgkmcnt
// drain). Block 256 thr = 16 lg (4 l each) x 16 og (12 oc each).
// grid (L/64, B, 2): z=0 -> xc half, z=1 -> silu(z) half.
__global__ __launch_bounds__(256) void k_inproj(const float* __restrict__ x,
        const float* __restrict__ W_in, float* __restrict__ xc_pre,
        float* __restrict__ z_silu) {
    __shared__ float lx[96*65];      // [c][l], pad 65 (conflict-free stage)
    __shared__ float wt[48*196];     // [cc][oc], pad 196 (4-aligned for b128)
    int b = blockIdx.y, z = blockIdx.z;
    int l0 = blockIdx.x * 64;
    int t = threadIdx.x;
    for (int i = 0; i < 24; ++i) {
        int e = t + 256*i;                 // 6144 = 64l x 96c, c fast
        int l = e / 96, c = e % 96;
        lx[c*65 + l] = x[((size_t)(b*LL + l0 + l))*96 + c];
    }
    int lg = t & 15;
    int og = t >> 4;
    float acc[4][12];
    #pragma unroll
    for (int j = 0; j < 4; ++j)
        #pragma unroll
        for (int q = 0; q < 12; ++q) acc[j][q] = 0.f;
    for (int p = 0; p < 2; ++p) {
        __syncthreads();
        for (int i = 0; i < 36; ++i) {
            int e = t + 256*i;             // 9216 = 48c x 192oc, c fast -> coalesced
            int cc = e % 48, oc = e / 48;
            wt[cc*196 + oc] = W_in[((size_t)(z*192 + oc))*96 + p*48 + cc];
        }
        __syncthreads();
        #pragma unroll 2
        for (int cc = 0; cc < 48; ++cc) {
            int c = p*48 + cc;
            float x0 = lx[c*65 + 4*lg + 0];
            float x1 = lx[c*65 + 4*lg + 1];
            float x2 = lx[c*65 + 4*lg + 2];
            float x3 = lx[c*65 + 4*lg + 3];
            const float* wr = &wt[cc*196 + 12*og];
            float4 w0 = *(const float4*)(wr);
            float4 w1 = *(const float4*)(wr + 4);
            float4 w2 = *(const float4*)(wr + 8);
            float wv[12] = {w0.x,w0.y,w0.z,w0.w, w1.x,w1.y,w1.z,w1.w,
                            w2.x,w2.y,w2.z,w2.w};
            #pragma unroll
            for (int q = 0; q < 12; ++q) {
                acc[0][q] += x0*wv[q];
                acc[1][q] += x1*wv[q];
                acc[2][q] += x2*wv[q];
                acc[3][q] += x3*wv[q];
            }
        }
    }
    float* dst = (z == 0) ? xc_pre : z_silu;
    #pragma unroll
    for (int j = 0; j < 4; ++j) {
        int l = l0 + 4*lg + j;
        size_t base = (size_t)(b*LL + l)*DIN + 12*og;
        #pragma unroll
        for (int q = 0; q < 12; ++q) {
            float v = acc[j][q];
            if (z) v = v / (1.f + __expf(-v));
            dst[base + q] = v;
        }
    }
}

// ---------------------------------------------------------------------------
// K2: depthwise 3x3 conv + bias + SiLU, [l][d] in/out.
__global__ __launch_bounds__(256) void k_conv(const float* __restrict__ xc,
        const float* __restrict__ cw, const float* __restrict__ cb,
        float* __restrict__ out) {
    int gid = blockIdx.x*256 + threadIdx.x;
    int d = gid % DIN;
    int r = gid / DIN;
    int l = r & 4095, b = r >> 12;
    int w = l & 63, h = l >> 6;
    float acc = cb[d];
    #pragma unroll
    for (int dh = -1; dh <= 1; ++dh) {
        int h2 = h + dh;
        bool okh = (h2 >= 0) && (h2 < 64);
        #pragma unroll
        for (int dw = -1; dw <= 1; ++dw) {
            int w2 = w + dw;
            if (okh && w2 >= 0 && w2 < 64)
                acc += xc[((size_t)(b*LL + h2*64 + w2))*DIN + d] * cw[d*9 + (dh+1)*3 + (dw+1)];
        }
    }
    out[((size_t)(b*LL + l))*DIN + d] = acc / (1.f + __expf(-acc));
}

// ---------------------------------------------------------------------------
// K3: x_proj + dt. 512 threads: lanes = 64 l, 8 wave-uniform row groups.
// xpw staged in LDS (same drain fix as K1).
__global__ __launch_bounds__(512) void k_proj(const float* __restrict__ xconv,
        const int* __restrict__ scan_ids,
        const float* __restrict__ xpw, const float* __restrict__ dtw,
        const float* __restrict__ dtb,
        float* __restrict__ Bs, float* __restrict__ Cs, float* __restrict__ delta) {
    __shared__ float lxs[DIN*65];    // [d][l]
    __shared__ float lw[RTOT*DIN];   // 38x192 weights, linear (b128-aligned rows)
    __shared__ float lbc[64*33];     // [l][32]: 0..15 B, 16..31 C
    __shared__ float ldts[RNK*64];   // [r][l]
    __shared__ int lsid[64];
    int k = blockIdx.y, b = blockIdx.z;
    int l0 = blockIdx.x * 64;
    int t = threadIdx.x;
    if (t < 64) lsid[t] = scan_ids[k*LL + l0 + t];
    for (int i = 0; i < 15; ++i) {
        int e = t + 512*i;
        if (e < RTOT*DIN) lw[e] = xpw[(size_t)k*RTOT*DIN + e];
    }
    __syncthreads();
    for (int i = 0; i < 24; ++i) {
        int e = t + 512*i;           // 12288 = 64l x 192d, d fast -> coalesced
        int d = e % DIN, l = e / DIN;
        lxs[d*65 + l] = xconv[((size_t)(b*LL + lsid[l]))*DIN + d];
    }
    __syncthreads();
    int l = t & 63;
    int rg = __builtin_amdgcn_readfirstlane(t >> 6);    // 0..7, wave-uniform
    float acc[5];
    #pragma unroll
    for (int j = 0; j < 5; ++j) acc[j] = 0.f;
    for (int d = 0; d < DIN; d += 4) {
        float x0 = lxs[(d+0)*65 + l];
        float x1 = lxs[(d+1)*65 + l];
        float x2 = lxs[(d+2)*65 + l];
        float x3 = lxs[(d+3)*65 + l];
        #pragma unroll
        for (int j = 0; j < 5; ++j) {
            int r = rg + 8*j;
            if (r < RTOT) {
                float4 w = *(const float4*)&lw[r*DIN + d];
                acc[j] += x0*w.x + x1*w.y + x2*w.z + x3*w.w;
            }
        }
    }
    #pragma unroll
    for (int j = 0; j < 5; ++j) {
        int r = rg + 8*j;
        if (r < RTOT) {
            if (r < RNK) ldts[r*64 + l] = acc[j];
            else         lbc[l*33 + (r - RNK)] = acc[j];
        }
    }
    __syncthreads();
    size_t rowb = ((size_t)((b*KK + k)*LL + l0))*NST;
    for (int i = 0; i < 2; ++i) {
        int e = t + 512*i;           // 1024 = 64l x 16n
        int n = e & 15, ll = e >> 4;
        Bs[rowb + ll*NST + n] = lbc[ll*33 + n];
        Cs[rowb + ll*NST + n] = lbc[ll*33 + 16 + n];
    }
    for (int i = 0; i < 24; ++i) {
        int e = t + 512*i;
        int d = e % DIN, ll = e / DIN;
        float a = dtb[k*DIN + d];
        #pragma unroll
        for (int r = 0; r < RNK; ++r)
            a += ldts[r*64 + ll] * dtw[(k*DIN + d)*RNK + r];
        float sp = fmaxf(a, 0.f) + __logf(1.f + __expf(-fabsf(a)));
        delta[((size_t)((b*KK + k)*LL + l0 + ll))*DIN + d] = sp;
    }
}

// ---------------------------------------------------------------------------
// K4: scan pass 1 — per-segment (prod e, partial h), one channel per lane.
__global__ __launch_bounds__(192) void k_scan1(const float* __restrict__ delta,
        const float* __restrict__ xconv, const float* __restrict__ Bs,
        const int* __restrict__ scan_ids, const float* __restrict__ A_logs,
        float* __restrict__ segA, float* __restrict__ segB, int SL) {
    __shared__ int lsid[256];
    int seg = blockIdx.x, bk = blockIdx.y;
    int b = bk >> 2, k = bk & 3;
    int d = threadIdx.x;
    int l0 = seg * SL;
    for (int i = threadIdx.x; i < SL; i += 192) lsid[i] = scan_ids[k*LL + l0 + i];
    __syncthreads();
    float Av[16];
    {
        const float4* ap = (const float4*)(A_logs + (k*DIN + d)*NST);
        #pragma unroll
        for (int q = 0; q < 4; ++q) {
            float4 v = ap[q];
            Av[4*q+0] = -__expf(v.x); Av[4*q+1] = -__expf(v.y);
            Av[4*q+2] = -__expf(v.z); Av[4*q+3] = -__expf(v.w);
        }
    }
    float a[16], h[16];
    #pragma unroll
    for (int n = 0; n < 16; ++n) { a[n] = 1.f; h[n] = 0.f; }
    const float* dp = delta + ((size_t)bk*LL + l0)*DIN + d;
    const float4* bq = (const float4*)(Bs + ((size_t)bk*LL + l0)*NST);
    for (int li = 0; li < SL; ++li) {
        float dv = dp[(size_t)li*DIN];
        float xv = xconv[((size_t)(b*LL + lsid[li]))*DIN + d];
        float dxv = dv * xv;
        float bb[16];
        #pragma unroll
        for (int q = 0; q < 4; ++q) {
            float4 v = bq[li*4 + q];
            bb[4*q+0] = v.x; bb[4*q+1] = v.y; bb[4*q+2] = v.z; bb[4*q+3] = v.w;
        }
        #pragma unroll
        for (int n = 0; n < 16; ++n) {
            float e = __expf(dv * Av[n]);
            a[n] *= e;
            h[n] = e*h[n] + dxv*bb[n];
        }
    }
    float4* sa = (float4*)(segA + (((size_t)bk*gridDim.x + seg)*DIN + d)*NST);
    float4* sb = (float4*)(segB + (((size_t)bk*gridDim.x + seg)*DIN + d)*NST);
    #pragma unroll
    for (int q = 0; q < 4; ++q) {
        sa[q] = make_float4(a[4*q], a[4*q+1], a[4*q+2], a[4*q+3]);
        sb[q] = make_float4(h[4*q], h[4*q+1], h[4*q+2], h[4*q+3]);
    }
}

// ---------------------------------------------------------------------------
// K5: compose segment carries -> initial state per segment
__global__ __launch_bounds__(256) void k_scan2(const float* __restrict__ segA,
        const float* __restrict__ segB, float* __restrict__ hinit, int SEGC) {
    int idx = blockIdx.x*256 + threadIdx.x;
    if (idx >= BB*KK*DIN*NST) return;
    int bk = idx / (DIN*NST);
    int dn = idx % (DIN*NST);
    float h = 0.f;
    for (int s = 0; s < SEGC; ++s) {
        size_t o = ((size_t)(bk*SEGC + s))*(DIN*NST) + dn;
        hinit[o] = h;
        h = segA[o]*h + segB[o];
    }
}

// ---------------------------------------------------------------------------
// K6: scan pass 3 — replay with h0, y = sum_n h*C + xs*D, coalesced scatter.
__global__ __launch_bounds__(192) void k_scan3(const float* __restrict__ delta,
        const float* __restrict__ xconv, const float* __restrict__ Bs,
        const float* __restrict__ Cs,
        const int* __restrict__ scan_ids, const float* __restrict__ A_logs,
        const float* __restrict__ Ds, const float* __restrict__ hinit,
        float* __restrict__ y_dirs, float* __restrict__ poolsum, int SL) {
    __shared__ int lsid[256];
    int seg = blockIdx.x, bk = blockIdx.y;
    int b = bk >> 2, k = bk & 3;
    int d = threadIdx.x;
    int l0 = seg * SL;
    for (int i = threadIdx.x; i < SL; i += 192) lsid[i] = scan_ids[k*LL + l0 + i];
    __syncthreads();
    float Av[16];
    {
        const float4* ap = (const float4*)(A_logs + (k*DIN + d)*NST);
        #pragma unroll
        for (int q = 0; q < 4; ++q) {
            float4 v = ap[q];
            Av[4*q+0] = -__expf(v.x); Av[4*q+1] = -__expf(v.y);
            Av[4*q+2] = -__expf(v.z); Av[4*q+3] = -__expf(v.w);
        }
    }
    float Dv = Ds[k*DIN + d];
    float h[16];
    {
        const float4* hp = (const float4*)(hinit + (((size_t)bk*gridDim.x + seg)*DIN + d)*NST);
        #pragma unroll
        for (int q = 0; q < 4; ++q) {
            float4 v = hp[q];
            h[4*q+0] = v.x; h[4*q+1] = v.y; h[4*q+2] = v.z; h[4*q+3] = v.w;
        }
    }
    const float* dp = delta + ((size_t)bk*LL + l0)*DIN + d;
    const float4* bq = (const float4*)(Bs + ((size_t)bk*LL + l0)*NST);
    const float4* cq = (const float4*)(Cs + ((size_t)bk*LL + l0)*NST);
    float pool = 0.f;
    for (int li = 0; li < SL; ++li) {
        float dv = dp[(size_t)li*DIN];
        int l = lsid[li];
        float xv = xconv[((size_t)(b*LL + l))*DIN + d];
        float dxv = dv * xv;
        float bb[16], cc[16];
        #pragma unroll
        for (int q = 0; q < 4; ++q) {
            float4 v = bq[li*4 + q];
            bb[4*q+0] = v.x; bb[4*q+1] = v.y; bb[4*q+2] = v.z; bb[4*q+3] = v.w;
            float4 u = cq[li*4 + q];
            cc[4*q+0] = u.x; cc[4*q+1] = u.y; cc[4*q+2] = u.z; cc[4*q+3] = u.w;
        }
        float y = 0.f;
        #pragma unroll
        for (int n = 0; n < 16; ++n) {
            float e = __expf(dv * Av[n]);
            h[n] = e*h[n] + dxv*bb[n];
            y += h[n]*cc[n];
        }
        y += xv * Dv;
        y_dirs[((size_t)(bk*LL + l))*DIN + d] = y;
        pool += y;
    }
    atomicAdd(&poolsum[(b*DIN + d)*KK + k], pool);
}

// ---------------------------------------------------------------------------
// K7: gate
__global__ void k_gate(const float* __restrict__ poolsum, const float* __restrict__ gw,
        const float* __restrict__ gb, float* __restrict__ gate) {
    int idx = blockIdx.x*256 + threadIdx.x;
    int o = idx & 3;
    int bd = idx >> 2;
    int d = bd % DIN;
    float acc = gb[d*KK + o];
    #pragma unroll
    for (int i = 0; i < KK; ++i)
        acc += (poolsum[bd*KK + i] * (1.f/LL)) * gw[(d*KK + o)*KK + i];
    gate[idx] = 1.f/(1.f + __expf(-acc));
}

// ---------------------------------------------------------------------------
// K8: y = sum_k gate*y_dirs ; LN ; * silu(z) ; @ W_out^T.
__global__ __launch_bounds__(256) void k_final(const float* __restrict__ y_dirs,
        const float* __restrict__ gate, const float* __restrict__ z_silu,
        const float* __restrict__ lng, const float* __restrict__ lnb,
        const float* __restrict__ Wout, float* __restrict__ out) {
    __shared__ float buf[16*193];
    __shared__ float lmu[16], lrs[16];
    int b = blockIdx.y;
    int l0 = blockIdx.x * 16;
    int t = threadIdx.x;
    for (int i = 0; i < 12; ++i) {
        int e = t + 256*i;
        int d = e % DIN, l = e / DIN;
        float acc = 0.f;
        #pragma unroll
        for (int k = 0; k < KK; ++k)
            acc += y_dirs[((size_t)((b*KK + k)*LL + l0 + l))*DIN + d] * gate[(b*DIN + d)*KK + k];
        buf[l*193 + d] = acc;
    }
    __syncthreads();
    int l2 = t >> 4, q = t & 15;
    float s = 0.f, s2 = 0.f;
    for (int i = 0; i < 12; ++i) {
        float v = buf[l2*193 + q + 16*i];
        s += v; s2 += v*v;
    }
    s += __shfl_xor(s, 1);  s2 += __shfl_xor(s2, 1);
    s += __shfl_xor(s, 2);  s2 += __shfl_xor(s2, 2);
    s += __shfl_xor(s, 4);  s2 += __shfl_xor(s2, 4);
    s += __shfl_xor(s, 8);  s2 += __shfl_xor(s2, 8);
    if (q == 0) {
        float mu = s * (1.f/DIN);
        float var = s2 * (1.f/DIN) - mu*mu;
        lmu[l2] = mu;
        lrs[l2] = rsqrtf(var + 1e-5f);
    }
    __syncthreads();
    for (int i = 0; i < 12; ++i) {
        int e = t + 256*i;
        int d = e % DIN, l = e / DIN;
        float v = buf[l*193 + d];
        float tv = (v - lmu[l]) * lrs[l] * lng[d] + lnb[d];
        tv *= z_silu[((size_t)(b*LL + l0 + l))*DIN + d];
        buf[l*193 + d] = tv;
    }
    __syncthreads();
    int l = t & 15;
    int c0 = (t >> 4) * 6;
    float acc[6];
    #pragma unroll
    for (int cc = 0; cc < 6; ++cc) acc[cc] = 0.f;
    for (int d = 0; d < DIN; ++d) {
        float v = buf[l*193 + d];
        #pragma unroll
        for (int cc = 0; cc < 6; ++cc)
            acc[cc] += v * Wout[(c0 + cc)*DIN + d];
    }
    #pragma unroll
    for (int cc = 0; cc < 6; ++cc)
        out[((size_t)(b*LL + l0 + l))*CC + c0 + cc] = acc[cc];
}

// ---------------------------------------------------------------------------
extern "C" void kernel_launch(void* const* d_in, const int* in_sizes, int n_in,
                              void* d_out, int out_size, void* d_ws, size_t ws_size,
                              hipStream_t stream) {
    const float* x      = (const float*)d_in[0];
    const float* W_in   = (const float*)d_in[1];
    const float* conv_w = (const float*)d_in[2];
    const float* conv_b = (const float*)d_in[3];
    const float* xpw    = (const float*)d_in[4];
    const float* dt_w   = (const float*)d_in[5];
    const float* dt_b   = (const float*)d_in[6];
    const float* A_logs = (const float*)d_in[7];
    const float* Ds     = (const float*)d_in[8];
    const float* gate_w = (const float*)d_in[9];
    const float* gate_b = (const float*)d_in[10];
    const float* ln_g   = (const float*)d_in[11];
    const float* ln_b   = (const float*)d_in[12];
    const float* W_out  = (const float*)d_in[13];
    const int* scan_ids = (const int*)d_in[14];
    float* out = (float*)d_out;

    const size_t baseF = 6291456ull /*y_dirs|xc_pre*/ + 2ull*1572864 /*z,xconv*/
                       + 6291456ull /*delta*/ + 2ull*524288 /*Bs,Cs*/ + 3072;
    int SEGC = 16;
    if ((baseF + 3ull*128*24576)*4 <= ws_size) SEGC = 128;
    else if ((baseF + 3ull*64*24576)*4 <= ws_size) SEGC = 64;
    else if ((baseF + 3ull*32*24576)*4 <= ws_size) SEGC = 32;
    int SL = LL / SEGC;
    size_t segF = (size_t)SEGC * 24576;

    float* ws      = (float*)d_ws;
    float* y_dirs  = ws;
    float* xc_pre  = ws;                       // alias (dead after k_conv)
    float* z_silu  = y_dirs  + 6291456;
    float* xconv   = z_silu  + 1572864;
    float* delta   = xconv   + 1572864;
    float* Bs      = delta   + 6291456;
    float* Cs      = Bs      + 524288;
    float* poolsum = Cs      + 524288;
    float* gate    = poolsum + 1536;
    float* segA    = gate    + 1536;
    float* segB    = segA    + segF;
    float* hinit   = segB    + segF;

    hipMemsetAsync(poolsum, 0, 1536*sizeof(float), stream);

    k_inproj<<<dim3(LL/64, BB, 2), 256, 0, stream>>>(x, W_in, xc_pre, z_silu);
    k_conv<<<(BB*DIN*LL)/256, 256, 0, stream>>>(xc_pre, conv_w, conv_b, xconv);
    k_proj<<<dim3(LL/64, KK, BB), 512, 0, stream>>>(xconv, scan_ids, xpw, dt_w, dt_b,
                                                    Bs, Cs, delta);
    k_scan1<<<dim3(SEGC, BB*KK), 192, 0, stream>>>(delta, xconv, Bs, scan_ids,
                                                   A_logs, segA, segB, SL);
    k_scan2<<<(BB*KK*DIN*NST + 255)/256, 256, 0, stream>>>(segA, segB, hinit, SEGC);
    k_scan3<<<dim3(SEGC, BB*KK), 192, 0, stream>>>(delta, xconv, Bs, Cs, scan_ids,
                                                   A_logs, Ds, hinit, y_dirs, poolsum, SL);
    k_gate<<<(BB*DIN*KK)/256, 256, 0, stream>>>(poolsum, gate_w, gate_b, gate);
    k_final<<<dim3(LL/16, BB), 256, 0, stream>>>(y_dirs, gate, z_silu, ln_g, ln_b, W_out, out);
}

// Round 5
// 284.246 us; speedup vs baseline: 2.0459x; 1.1239x over previous
//
#include <hip/hip_runtime.h>
#include <math.h>

#define BB 2
#define CC 96
#define DIN 192
#define NST 16
#define RNK 6
#define KK 4
#define LL 4096
#define RTOT (RNK + 2*NST)   // 38

// Scratch layouts:
//   xc_pre (aliases y_dirs), z_silu, xconv : [b][l][DIN]
//   dts    : [bk][l_scan][8]  (6 used)
//   Bs, Cs : [bk][l_scan][NST]
//   segA/segB/hinit : [bk][seg][d][NST]
//   y_dirs : [bk][l_spatial][DIN]

// ---------------------------------------------------------------------------
// K1: in_proj, weights staged in LDS. 256 thr = 16 lg (4 l) x 16 og (12 oc).
__global__ __launch_bounds__(256) void k_inproj(const float* __restrict__ x,
        const float* __restrict__ W_in, float* __restrict__ xc_pre,
        float* __restrict__ z_silu) {
    __shared__ float lx[96*65];
    __shared__ float wt[48*196];
    int b = blockIdx.y, z = blockIdx.z;
    int l0 = blockIdx.x * 64;
    int t = threadIdx.x;
    for (int i = 0; i < 24; ++i) {
        int e = t + 256*i;
        int l = e / 96, c = e % 96;
        lx[c*65 + l] = x[((size_t)(b*LL + l0 + l))*96 + c];
    }
    int lg = t & 15;
    int og = t >> 4;
    float acc[4][12];
    #pragma unroll
    for (int j = 0; j < 4; ++j)
        #pragma unroll
        for (int q = 0; q < 12; ++q) acc[j][q] = 0.f;
    for (int p = 0; p < 2; ++p) {
        __syncthreads();
        for (int i = 0; i < 36; ++i) {
            int e = t + 256*i;
            int cc = e % 48, oc = e / 48;
            wt[cc*196 + oc] = W_in[((size_t)(z*192 + oc))*96 + p*48 + cc];
        }
        __syncthreads();
        #pragma unroll 2
        for (int cc = 0; cc < 48; ++cc) {
            int c = p*48 + cc;
            float x0 = lx[c*65 + 4*lg + 0];
            float x1 = lx[c*65 + 4*lg + 1];
            float x2 = lx[c*65 + 4*lg + 2];
            float x3 = lx[c*65 + 4*lg + 3];
            const float* wr = &wt[cc*196 + 12*og];
            float4 w0 = *(const float4*)(wr);
            float4 w1 = *(const float4*)(wr + 4);
            float4 w2 = *(const float4*)(wr + 8);
            float wv[12] = {w0.x,w0.y,w0.z,w0.w, w1.x,w1.y,w1.z,w1.w,
                            w2.x,w2.y,w2.z,w2.w};
            #pragma unroll
            for (int q = 0; q < 12; ++q) {
                acc[0][q] += x0*wv[q];
                acc[1][q] += x1*wv[q];
                acc[2][q] += x2*wv[q];
                acc[3][q] += x3*wv[q];
            }
        }
    }
    float* dst = (z == 0) ? xc_pre : z_silu;
    #pragma unroll
    for (int j = 0; j < 4; ++j) {
        int l = l0 + 4*lg + j;
        size_t base = (size_t)(b*LL + l)*DIN + 12*og;
        #pragma unroll
        for (int q = 0; q < 12; ++q) {
            float v = acc[j][q];
            if (z) v = v / (1.f + __expf(-v));
            dst[base + q] = v;
        }
    }
}

// ---------------------------------------------------------------------------
// K2: depthwise 3x3 conv + bias + SiLU, [l][d] in/out.
__global__ __launch_bounds__(256) void k_conv(const float* __restrict__ xc,
        const float* __restrict__ cw, const float* __restrict__ cb,
        float* __restrict__ out) {
    int gid = blockIdx.x*256 + threadIdx.x;
    int d = gid % DIN;
    int r = gid / DIN;
    int l = r & 4095, b = r >> 12;
    int w = l & 63, h = l >> 6;
    float acc = cb[d];
    #pragma unroll
    for (int dh = -1; dh <= 1; ++dh) {
        int h2 = h + dh;
        bool okh = (h2 >= 0) && (h2 < 64);
        #pragma unroll
        for (int dw = -1; dw <= 1; ++dw) {
            int w2 = w + dw;
            if (okh && w2 >= 0 && w2 < 64)
                acc += xc[((size_t)(b*LL + h2*64 + w2))*DIN + d] * cw[d*9 + (dh+1)*3 + (dw+1)];
        }
    }
    out[((size_t)(b*LL + l))*DIN + d] = acc / (1.f + __expf(-acc));
}

// ---------------------------------------------------------------------------
// K3: x_proj GEMV -> dts (global, 6/8 floats) + Bs/Cs. Two d-phases of 96 to
// keep LDS ~47 KB (3 blocks/CU). No delta materialization.
__global__ __launch_bounds__(512) void k_proj(const float* __restrict__ xconv,
        const int* __restrict__ scan_ids, const float* __restrict__ xpw,
        float* __restrict__ dts, float* __restrict__ Bs, float* __restrict__ Cs) {
    __shared__ float lxs[96*65];     // [dd][l] phase tile
    __shared__ float lw[RTOT*96];    // [r][dd] phase tile
    __shared__ float lbc[64*33];     // [l][32]: 0..15 B, 16..31 C
    __shared__ int lsid[64];
    int k = blockIdx.y, b = blockIdx.z;
    int l0 = blockIdx.x * 64;
    int t = threadIdx.x;
    if (t < 64) lsid[t] = scan_ids[k*LL + l0 + t];
    int l = t & 63;
    int rg = __builtin_amdgcn_readfirstlane(t >> 6);    // 0..7, wave-uniform
    float acc[5];
    #pragma unroll
    for (int j = 0; j < 5; ++j) acc[j] = 0.f;
    for (int p = 0; p < 2; ++p) {
        __syncthreads();
        for (int i = 0; i < 12; ++i) {
            int e = t + 512*i;               // 6144 = 64l x 96dd, dd fast
            int dd = e % 96, ll = e / 96;
            lxs[dd*65 + ll] = xconv[((size_t)(b*LL + lsid[ll]))*DIN + p*96 + dd];
        }
        for (int i = 0; i < 8; ++i) {
            int e = t + 512*i;               // 3648 = 38r x 96dd
            if (e < RTOT*96) {
                int r = e / 96, dd = e % 96;
                lw[r*96 + dd] = xpw[(size_t)k*RTOT*DIN + r*DIN + p*96 + dd];
            }
        }
        __syncthreads();
        for (int dd = 0; dd < 96; dd += 4) {
            float x0 = lxs[(dd+0)*65 + l];
            float x1 = lxs[(dd+1)*65 + l];
            float x2 = lxs[(dd+2)*65 + l];
            float x3 = lxs[(dd+3)*65 + l];
            #pragma unroll
            for (int j = 0; j < 5; ++j) {
                int r = rg + 8*j;
                if (r < RTOT) {
                    float4 w = *(const float4*)&lw[r*96 + dd];
                    acc[j] += x0*w.x + x1*w.y + x2*w.z + x3*w.w;
                }
            }
        }
    }
    int bk = b*KK + k;
    #pragma unroll
    for (int j = 0; j < 5; ++j) {
        int r = rg + 8*j;
        if (r < RNK)       dts[((size_t)bk*LL + l0 + l)*8 + r] = acc[j];
        else if (r < RTOT) lbc[l*33 + (r - RNK)] = acc[j];
    }
    __syncthreads();
    size_t rowb = ((size_t)bk*LL + l0)*NST;
    for (int i = 0; i < 2; ++i) {
        int e = t + 512*i;                   // 1024 = 64l x 16n
        int n = e & 15, ll = e >> 4;
        Bs[rowb + ll*NST + n] = lbc[ll*33 + n];
        Cs[rowb + ll*NST + n] = lbc[ll*33 + 16 + n];
    }
}

// ---------------------------------------------------------------------------
// K4: scan pass 1. 384 thr = (d = t>>1) x (half = t&1, 8 states each).
// delta recomputed from dts in per-chunk LDS staging; x gather prefetched.
__global__ __launch_bounds__(384) void k_scan1(const float* __restrict__ xconv,
        const float* __restrict__ Bs, const float* __restrict__ dts,
        const float* __restrict__ dtw, const float* __restrict__ dtb,
        const int* __restrict__ scan_ids, const float* __restrict__ A_logs,
        float* __restrict__ segA, float* __restrict__ segB, int SL) {
    __shared__ float ldel[32*DIN];
    __shared__ float lB[32*NST];
    __shared__ int lsid[256];
    int seg = blockIdx.x, bk = blockIdx.y;
    int b = bk >> 2, k = bk & 3;
    int t = threadIdx.x;
    int half = t & 1, d = t >> 1;
    int l0 = seg * SL;
    for (int i = t; i < SL; i += 384) lsid[i] = scan_ids[k*LL + l0 + i];
    float Av[8];
    {
        const float4* ap = (const float4*)(A_logs + ((k*DIN + d)*NST + half*8));
        float4 a0 = ap[0], a1 = ap[1];
        Av[0]=-__expf(a0.x); Av[1]=-__expf(a0.y); Av[2]=-__expf(a0.z); Av[3]=-__expf(a0.w);
        Av[4]=-__expf(a1.x); Av[5]=-__expf(a1.y); Av[6]=-__expf(a1.z); Av[7]=-__expf(a1.w);
    }
    int dd = t % DIN, li0 = t / DIN;         // staging role: fixed dd, li += 2
    float wdt[RNK];
    float bdt = dtb[k*DIN + dd];
    #pragma unroll
    for (int r = 0; r < RNK; ++r) wdt[r] = dtw[(k*DIN + dd)*RNK + r];
    float a[8], h[8];
    #pragma unroll
    for (int n = 0; n < 8; ++n) { a[n] = 1.f; h[n] = 0.f; }
    __syncthreads();
    float xn = xconv[((size_t)(b*LL + lsid[0]))*DIN + d];
    for (int c0 = 0; c0 < SL; c0 += 32) {
        for (int li = li0; li < 32; li += 2) {
            const float* dr = dts + ((size_t)bk*LL + l0 + c0 + li)*8;
            float aa = bdt;
            #pragma unroll
            for (int r = 0; r < RNK; ++r) aa += dr[r]*wdt[r];
            ldel[li*DIN + dd] = fmaxf(aa, 0.f) + __logf(1.f + __expf(-fabsf(aa)));
        }
        for (int e = t; e < 32*NST; e += 384)
            lB[e] = Bs[((size_t)bk*LL + l0 + c0)*NST + e];
        __syncthreads();
        for (int li2 = 0; li2 < 32; ++li2) {
            int li = c0 + li2;
            float xv = xn;
            if (li + 1 < SL) xn = xconv[((size_t)(b*LL + lsid[li+1]))*DIN + d];
            float dv = ldel[li2*DIN + d];
            float dxv = dv * xv;
            float4 b0 = *(const float4*)&lB[li2*NST + half*8];
            float4 b1 = *(const float4*)&lB[li2*NST + half*8 + 4];
            float bb[8] = {b0.x,b0.y,b0.z,b0.w, b1.x,b1.y,b1.z,b1.w};
            #pragma unroll
            for (int n = 0; n < 8; ++n) {
                float e2 = __expf(dv * Av[n]);
                a[n] *= e2;
                h[n] = e2*h[n] + dxv*bb[n];
            }
        }
        __syncthreads();
    }
    size_t base = (((size_t)bk*gridDim.x + seg)*DIN + d)*NST + half*8;
    *(float4*)&segA[base]     = make_float4(a[0],a[1],a[2],a[3]);
    *(float4*)&segA[base + 4] = make_float4(a[4],a[5],a[6],a[7]);
    *(float4*)&segB[base]     = make_float4(h[0],h[1],h[2],h[3]);
    *(float4*)&segB[base + 4] = make_float4(h[4],h[5],h[6],h[7]);
}

// ---------------------------------------------------------------------------
// K5: compose segment carries -> initial state per segment
__global__ __launch_bounds__(256) void k_scan2(const float* __restrict__ segA,
        const float* __restrict__ segB, float* __restrict__ hinit, int SEGC) {
    int idx = blockIdx.x*256 + threadIdx.x;
    if (idx >= BB*KK*DIN*NST) return;
    int bk = idx / (DIN*NST);
    int dn = idx % (DIN*NST);
    float h = 0.f;
    #pragma unroll 4
    for (int s = 0; s < SEGC; ++s) {
        size_t o = ((size_t)(bk*SEGC + s))*(DIN*NST) + dn;
        hinit[o] = h;
        h = segA[o]*h + segB[o];
    }
}

// ---------------------------------------------------------------------------
// K6: scan pass 3 — replay with h0, y = sum_n h*C + xs*D (pair-shfl reduce),
// coalesced scatter to spatial [l][d], pool accumulation.
__global__ __launch_bounds__(384) void k_scan3(const float* __restrict__ xconv,
        const float* __restrict__ Bs, const float* __restrict__ Cs,
        const float* __restrict__ dts, const float* __restrict__ dtw,
        const float* __restrict__ dtb,
        const int* __restrict__ scan_ids, const float* __restrict__ A_logs,
        const float* __restrict__ Ds, const float* __restrict__ hinit,
        float* __restrict__ y_dirs, float* __restrict__ poolsum, int SL) {
    __shared__ float ldel[32*DIN];
    __shared__ float lB[32*NST];
    __shared__ float lC[32*NST];
    __shared__ int lsid[256];
    int seg = blockIdx.x, bk = blockIdx.y;
    int b = bk >> 2, k = bk & 3;
    int t = threadIdx.x;
    int half = t & 1, d = t >> 1;
    int l0 = seg * SL;
    for (int i = t; i < SL; i += 384) lsid[i] = scan_ids[k*LL + l0 + i];
    float Av[8];
    {
        const float4* ap = (const float4*)(A_logs + ((k*DIN + d)*NST + half*8));
        float4 a0 = ap[0], a1 = ap[1];
        Av[0]=-__expf(a0.x); Av[1]=-__expf(a0.y); Av[2]=-__expf(a0.z); Av[3]=-__expf(a0.w);
        Av[4]=-__expf(a1.x); Av[5]=-__expf(a1.y); Av[6]=-__expf(a1.z); Av[7]=-__expf(a1.w);
    }
    float Dv = Ds[k*DIN + d];
    int dd = t % DIN, li0 = t / DIN;
    float wdt[RNK];
    float bdt = dtb[k*DIN + dd];
    #pragma unroll
    for (int r = 0; r < RNK; ++r) wdt[r] = dtw[(k*DIN + dd)*RNK + r];
    float h[8];
    {
        size_t base = (((size_t)bk*gridDim.x + seg)*DIN + d)*NST + half*8;
        float4 h0 = *(const float4*)&hinit[base];
        float4 h1 = *(const float4*)&hinit[base + 4];
        h[0]=h0.x; h[1]=h0.y; h[2]=h0.z; h[3]=h0.w;
        h[4]=h1.x; h[5]=h1.y; h[6]=h1.z; h[7]=h1.w;
    }
    __syncthreads();
    float xn = xconv[((size_t)(b*LL + lsid[0]))*DIN + d];
    float pool = 0.f;
    for (int c0 = 0; c0 < SL; c0 += 32) {
        for (int li = li0; li < 32; li += 2) {
            const float* dr = dts + ((size_t)bk*LL + l0 + c0 + li)*8;
            float aa = bdt;
            #pragma unroll
            for (int r = 0; r < RNK; ++r) aa += dr[r]*wdt[r];
            ldel[li*DIN + dd] = fmaxf(aa, 0.f) + __logf(1.f + __expf(-fabsf(aa)));
        }
        for (int e = t; e < 32*NST; e += 384) {
            lB[e] = Bs[((size_t)bk*LL + l0 + c0)*NST + e];
            lC[e] = Cs[((size_t)bk*LL + l0 + c0)*NST + e];
        }
        __syncthreads();
        for (int li2 = 0; li2 < 32; ++li2) {
            int li = c0 + li2;
            int l = lsid[li];
            float xv = xn;
            if (li + 1 < SL) xn = xconv[((size_t)(b*LL + lsid[li+1]))*DIN + d];
            float dv = ldel[li2*DIN + d];
            float dxv = dv * xv;
            float4 b0 = *(const float4*)&lB[li2*NST + half*8];
            float4 b1 = *(const float4*)&lB[li2*NST + half*8 + 4];
            float4 c0v = *(const float4*)&lC[li2*NST + half*8];
            float4 c1v = *(const float4*)&lC[li2*NST + half*8 + 4];
            float bb[8] = {b0.x,b0.y,b0.z,b0.w, b1.x,b1.y,b1.z,b1.w};
            float cc[8] = {c0v.x,c0v.y,c0v.z,c0v.w, c1v.x,c1v.y,c1v.z,c1v.w};
            float y = 0.f;
            #pragma unroll
            for (int n = 0; n < 8; ++n) {
                float e2 = __expf(dv * Av[n]);
                h[n] = e2*h[n] + dxv*bb[n];
                y += h[n]*cc[n];
            }
            y += __shfl_xor(y, 1);
            if (half == 0) {
                y += xv * Dv;
                y_dirs[((size_t)(bk*LL + l))*DIN + d] = y;
                pool += y;
            }
        }
        __syncthreads();
    }
    if (half == 0) atomicAdd(&poolsum[(b*DIN + d)*KK + k], pool);
}

// ---------------------------------------------------------------------------
// K7: gate
__global__ void k_gate(const float* __restrict__ poolsum, const float* __restrict__ gw,
        const float* __restrict__ gb, float* __restrict__ gate) {
    int idx = blockIdx.x*256 + threadIdx.x;
    int o = idx & 3;
    int bd = idx >> 2;
    int d = bd % DIN;
    float acc = gb[d*KK + o];
    #pragma unroll
    for (int i = 0; i < KK; ++i)
        acc += (poolsum[bd*KK + i] * (1.f/LL)) * gw[(d*KK + o)*KK + i];
    gate[idx] = 1.f/(1.f + __expf(-acc));
}

// ---------------------------------------------------------------------------
// K8: y = sum_k gate*y_dirs ; LN ; * silu(z) ; @ W_out^T.
__global__ __launch_bounds__(256) void k_final(const float* __restrict__ y_dirs,
        const float* __restrict__ gate, const float* __restrict__ z_silu,
        const float* __restrict__ lng, const float* __restrict__ lnb,
        const float* __restrict__ Wout, float* __restrict__ out) {
    __shared__ float buf[16*193];
    __shared__ float lmu[16], lrs[16];
    int b = blockIdx.y;
    int l0 = blockIdx.x * 16;
    int t = threadIdx.x;
    for (int i = 0; i < 12; ++i) {
        int e = t + 256*i;
        int d = e % DIN, l = e / DIN;
        float acc = 0.f;
        #pragma unroll
        for (int k = 0; k < KK; ++k)
            acc += y_dirs[((size_t)((b*KK + k)*LL + l0 + l))*DIN + d] * gate[(b*DIN + d)*KK + k];
        buf[l*193 + d] = acc;
    }
    __syncthreads();
    int l2 = t >> 4, q = t & 15;
    float s = 0.f, s2 = 0.f;
    for (int i = 0; i < 12; ++i) {
        float v = buf[l2*193 + q + 16*i];
        s += v; s2 += v*v;
    }
    s += __shfl_xor(s, 1);  s2 += __shfl_xor(s2, 1);
    s += __shfl_xor(s, 2);  s2 += __shfl_xor(s2, 2);
    s += __shfl_xor(s, 4);  s2 += __shfl_xor(s2, 4);
    s += __shfl_xor(s, 8);  s2 += __shfl_xor(s2, 8);
    if (q == 0) {
        float mu = s * (1.f/DIN);
        float var = s2 * (1.f/DIN) - mu*mu;
        lmu[l2] = mu;
        lrs[l2] = rsqrtf(var + 1e-5f);
    }
    __syncthreads();
    for (int i = 0; i < 12; ++i) {
        int e = t + 256*i;
        int d = e % DIN, l = e / DIN;
        float v = buf[l*193 + d];
        float tv = (v - lmu[l]) * lrs[l] * lng[d] + lnb[d];
        tv *= z_silu[((size_t)(b*LL + l0 + l))*DIN + d];
        buf[l*193 + d] = tv;
    }
    __syncthreads();
    int l = t & 15;
    int c0 = (t >> 4) * 6;
    float acc[6];
    #pragma unroll
    for (int cc = 0; cc < 6; ++cc) acc[cc] = 0.f;
    for (int d = 0; d < DIN; ++d) {
        float v = buf[l*193 + d];
        #pragma unroll
        for (int cc = 0; cc < 6; ++cc)
            acc[cc] += v * Wout[(c0 + cc)*DIN + d];
    }
    #pragma unroll
    for (int cc = 0; cc < 6; ++cc)
        out[((size_t)(b*LL + l0 + l))*CC + c0 + cc] = acc[cc];
}

// ---------------------------------------------------------------------------
extern "C" void kernel_launch(void* const* d_in, const int* in_sizes, int n_in,
                              void* d_out, int out_size, void* d_ws, size_t ws_size,
                              hipStream_t stream) {
    const float* x      = (const float*)d_in[0];
    const float* W_in   = (const float*)d_in[1];
    const float* conv_w = (const float*)d_in[2];
    const float* conv_b = (const float*)d_in[3];
    const float* xpw    = (const float*)d_in[4];
    const float* dt_w   = (const float*)d_in[5];
    const float* dt_b   = (const float*)d_in[6];
    const float* A_logs = (const float*)d_in[7];
    const float* Ds     = (const float*)d_in[8];
    const float* gate_w = (const float*)d_in[9];
    const float* gate_b = (const float*)d_in[10];
    const float* ln_g   = (const float*)d_in[11];
    const float* ln_b   = (const float*)d_in[12];
    const float* W_out  = (const float*)d_in[13];
    const int* scan_ids = (const int*)d_in[14];
    float* out = (float*)d_out;

    // baseF: y_dirs + z_silu + xconv + dts + Bs + Cs + poolsum + gate
    const size_t baseF = 6291456ull + 2ull*1572864 + 262144ull + 2ull*524288 + 3072;
    int SEGC = 16;
    if ((baseF + 3ull*128*24576)*4 <= ws_size) SEGC = 128;
    else if ((baseF + 3ull*64*24576)*4 <= ws_size) SEGC = 64;
    else if ((baseF + 3ull*32*24576)*4 <= ws_size) SEGC = 32;
    int SL = LL / SEGC;
    size_t segF = (size_t)SEGC * 24576;

    float* ws      = (float*)d_ws;
    float* y_dirs  = ws;
    float* xc_pre  = ws;                       // alias (dead after k_conv)
    float* z_silu  = y_dirs  + 6291456;
    float* xconv   = z_silu  + 1572864;
    float* dts     = xconv   + 1572864;        // [bk][l][8]
    float* Bs      = dts     + 262144;
    float* Cs      = Bs      + 524288;
    float* poolsum = Cs      + 524288;
    float* gate    = poolsum + 1536;
    float* segA    = gate    + 1536;
    float* segB    = segA    + segF;
    float* hinit   = segB    + segF;

    hipMemsetAsync(poolsum, 0, 1536*sizeof(float), stream);

    k_inproj<<<dim3(LL/64, BB, 2), 256, 0, stream>>>(x, W_in, xc_pre, z_silu);
    k_conv<<<(BB*DIN*LL)/256, 256, 0, stream>>>(xc_pre, conv_w, conv_b, xconv);
    k_proj<<<dim3(LL/64, KK, BB), 512, 0, stream>>>(xconv, scan_ids, xpw,
                                                    dts, Bs, Cs);
    k_scan1<<<dim3(SEGC, BB*KK), 384, 0, stream>>>(xconv, Bs, dts, dt_w, dt_b,
                                                   scan_ids, A_logs, segA, segB, SL);
    k_scan2<<<(BB*KK*DIN*NST + 255)/256, 256, 0, stream>>>(segA, segB, hinit, SEGC);
    k_scan3<<<dim3(SEGC, BB*KK), 384, 0, stream>>>(xconv, Bs, Cs, dts, dt_w, dt_b,
                                                   scan_ids, A_logs, Ds, hinit,
                                                   y_dirs, poolsum, SL);
    k_gate<<<(BB*DIN*KK)/256, 256, 0, stream>>>(poolsum, gate_w, gate_b, gate);
    k_final<<<dim3(LL/16, BB), 256, 0, stream>>>(y_dirs, gate, z_silu, ln_g, ln_b, W_out, out);
}

// Round 6
// 282.972 us; speedup vs baseline: 2.0551x; 1.0045x over previous
//
#include <hip/hip_runtime.h>
#include <math.h>

#define BB 2
#define CC 96
#define DIN 192
#define NST 16
#define RNK 6
#define KK 4
#define LL 4096
#define RTOT (RNK + 2*NST)   // 38

// Scratch layouts:
//   xc_pre (aliases y_dirs), z_silu, xconv : [b][l][DIN]
//   dts    : [bk][l_scan][8]  (6 used)
//   Bs, Cs : [bk][l_scan][NST]
//   segA/segB/hinit : [bk][seg][d][NST]
//   y_dirs : [bk][l_spatial][DIN]

// ---------------------------------------------------------------------------
// K1: in_proj, weights staged in LDS. 256 thr = 16 lg (4 l) x 16 og (12 oc).
__global__ __launch_bounds__(256) void k_inproj(const float* __restrict__ x,
        const float* __restrict__ W_in, float* __restrict__ xc_pre,
        float* __restrict__ z_silu) {
    __shared__ float lx[96*65];
    __shared__ float wt[48*196];
    int b = blockIdx.y, z = blockIdx.z;
    int l0 = blockIdx.x * 64;
    int t = threadIdx.x;
    for (int i = 0; i < 24; ++i) {
        int e = t + 256*i;
        int l = e / 96, c = e % 96;
        lx[c*65 + l] = x[((size_t)(b*LL + l0 + l))*96 + c];
    }
    int lg = t & 15;
    int og = t >> 4;
    float acc[4][12];
    #pragma unroll
    for (int j = 0; j < 4; ++j)
        #pragma unroll
        for (int q = 0; q < 12; ++q) acc[j][q] = 0.f;
    for (int p = 0; p < 2; ++p) {
        __syncthreads();
        for (int i = 0; i < 36; ++i) {
            int e = t + 256*i;
            int cc = e % 48, oc = e / 48;
            wt[cc*196 + oc] = W_in[((size_t)(z*192 + oc))*96 + p*48 + cc];
        }
        __syncthreads();
        #pragma unroll 2
        for (int cc = 0; cc < 48; ++cc) {
            int c = p*48 + cc;
            float x0 = lx[c*65 + 4*lg + 0];
            float x1 = lx[c*65 + 4*lg + 1];
            float x2 = lx[c*65 + 4*lg + 2];
            float x3 = lx[c*65 + 4*lg + 3];
            const float* wr = &wt[cc*196 + 12*og];
            float4 w0 = *(const float4*)(wr);
            float4 w1 = *(const float4*)(wr + 4);
            float4 w2 = *(const float4*)(wr + 8);
            float wv[12] = {w0.x,w0.y,w0.z,w0.w, w1.x,w1.y,w1.z,w1.w,
                            w2.x,w2.y,w2.z,w2.w};
            #pragma unroll
            for (int q = 0; q < 12; ++q) {
                acc[0][q] += x0*wv[q];
                acc[1][q] += x1*wv[q];
                acc[2][q] += x2*wv[q];
                acc[3][q] += x3*wv[q];
            }
        }
    }
    float* dst = (z == 0) ? xc_pre : z_silu;
    #pragma unroll
    for (int j = 0; j < 4; ++j) {
        int l = l0 + 4*lg + j;
        size_t base = (size_t)(b*LL + l)*DIN + 12*og;
        #pragma unroll
        for (int q = 0; q < 12; ++q) {
            float v = acc[j][q];
            if (z) v = v / (1.f + __expf(-v));
            dst[base + q] = v;
        }
    }
}

// ---------------------------------------------------------------------------
// K2: depthwise 3x3 conv + bias + SiLU, [l][d] in/out.
__global__ __launch_bounds__(256) void k_conv(const float* __restrict__ xc,
        const float* __restrict__ cw, const float* __restrict__ cb,
        float* __restrict__ out) {
    int gid = blockIdx.x*256 + threadIdx.x;
    int d = gid % DIN;
    int r = gid / DIN;
    int l = r & 4095, b = r >> 12;
    int w = l & 63, h = l >> 6;
    float acc = cb[d];
    #pragma unroll
    for (int dh = -1; dh <= 1; ++dh) {
        int h2 = h + dh;
        bool okh = (h2 >= 0) && (h2 < 64);
        #pragma unroll
        for (int dw = -1; dw <= 1; ++dw) {
            int w2 = w + dw;
            if (okh && w2 >= 0 && w2 < 64)
                acc += xc[((size_t)(b*LL + h2*64 + w2))*DIN + d] * cw[d*9 + (dh+1)*3 + (dw+1)];
        }
    }
    out[((size_t)(b*LL + l))*DIN + d] = acc / (1.f + __expf(-acc));
}

// ---------------------------------------------------------------------------
// K3: x_proj GEMV -> dts + Bs/Cs. Two d-phases of 96, LDS ~47 KB.
__global__ __launch_bounds__(512) void k_proj(const float* __restrict__ xconv,
        const int* __restrict__ scan_ids, const float* __restrict__ xpw,
        float* __restrict__ dts, float* __restrict__ Bs, float* __restrict__ Cs) {
    __shared__ float lxs[96*65];
    __shared__ float lw[RTOT*96];
    __shared__ float lbc[64*33];
    __shared__ int lsid[64];
    int k = blockIdx.y, b = blockIdx.z;
    int l0 = blockIdx.x * 64;
    int t = threadIdx.x;
    if (t < 64) lsid[t] = scan_ids[k*LL + l0 + t];
    int l = t & 63;
    int rg = __builtin_amdgcn_readfirstlane(t >> 6);
    float acc[5];
    #pragma unroll
    for (int j = 0; j < 5; ++j) acc[j] = 0.f;
    for (int p = 0; p < 2; ++p) {
        __syncthreads();
        for (int i = 0; i < 12; ++i) {
            int e = t + 512*i;
            int dd = e % 96, ll = e / 96;
            lxs[dd*65 + ll] = xconv[((size_t)(b*LL + lsid[ll]))*DIN + p*96 + dd];
        }
        for (int i = 0; i < 8; ++i) {
            int e = t + 512*i;
            if (e < RTOT*96) {
                int r = e / 96, dd = e % 96;
                lw[r*96 + dd] = xpw[(size_t)k*RTOT*DIN + r*DIN + p*96 + dd];
            }
        }
        __syncthreads();
        for (int dd = 0; dd < 96; dd += 4) {
            float x0 = lxs[(dd+0)*65 + l];
            float x1 = lxs[(dd+1)*65 + l];
            float x2 = lxs[(dd+2)*65 + l];
            float x3 = lxs[(dd+3)*65 + l];
            #pragma unroll
            for (int j = 0; j < 5; ++j) {
                int r = rg + 8*j;
                if (r < RTOT) {
                    float4 w = *(const float4*)&lw[r*96 + dd];
                    acc[j] += x0*w.x + x1*w.y + x2*w.z + x3*w.w;
                }
            }
        }
    }
    int bk = b*KK + k;
    #pragma unroll
    for (int j = 0; j < 5; ++j) {
        int r = rg + 8*j;
        if (r < RNK)       dts[((size_t)bk*LL + l0 + l)*8 + r] = acc[j];
        else if (r < RTOT) lbc[l*33 + (r - RNK)] = acc[j];
    }
    __syncthreads();
    size_t rowb = ((size_t)bk*LL + l0)*NST;
    for (int i = 0; i < 2; ++i) {
        int e = t + 512*i;
        int n = e & 15, ll = e >> 4;
        Bs[rowb + ll*NST + n] = lbc[ll*33 + n];
        Cs[rowb + ll*NST + n] = lbc[ll*33 + 16 + n];
    }
}

// ---------------------------------------------------------------------------
// K4: scan pass 1. 384 thr = (d = t>>1) x (half = t&1, 8 states each).
// Fast path: A[n] = (n+1)*A[0] (verified per-wave) -> 1 exp + power chain.
// Segment A-product via sumdv: a[n] = exp(Av[n] * sum(dv)).
__global__ __launch_bounds__(384) void k_scan1(const float* __restrict__ xconv,
        const float* __restrict__ Bs, const float* __restrict__ dts,
        const float* __restrict__ dtw, const float* __restrict__ dtb,
        const int* __restrict__ scan_ids, const float* __restrict__ A_logs,
        float* __restrict__ segA, float* __restrict__ segB, int SL) {
    __shared__ float ldel[32*DIN];
    __shared__ float lB[32*NST];
    __shared__ int lsid[256];
    int seg = blockIdx.x, bk = blockIdx.y;
    int b = bk >> 2, k = bk & 3;
    int t = threadIdx.x;
    int half = t & 1, d = t >> 1;
    int l0 = seg * SL;
    for (int i = t; i < SL; i += 384) lsid[i] = scan_ids[k*LL + l0 + i];
    float Av[8];
    {
        const float4* ap = (const float4*)(A_logs + ((k*DIN + d)*NST + half*8));
        float4 a0 = ap[0], a1 = ap[1];
        Av[0]=-__expf(a0.x); Av[1]=-__expf(a0.y); Av[2]=-__expf(a0.z); Av[3]=-__expf(a0.w);
        Av[4]=-__expf(a1.x); Av[5]=-__expf(a1.y); Av[6]=-__expf(a1.z); Av[7]=-__expf(a1.w);
    }
    float Av0 = -__expf(A_logs[(k*DIN + d)*NST]);
    bool okl = true;
    #pragma unroll
    for (int q = 0; q < 8; ++q) {
        float m = (float)(half*8 + q + 1);
        okl = okl && (fabsf(Av[q] - m*Av0) <= 1e-4f*m);
    }
    int fast = __all(okl);
    int dd = t % DIN, li0 = t / DIN;
    float wdt[RNK];
    float bdt = dtb[k*DIN + dd];
    #pragma unroll
    for (int r = 0; r < RNK; ++r) wdt[r] = dtw[(k*DIN + dd)*RNK + r];
    float h[8];
    #pragma unroll
    for (int n = 0; n < 8; ++n) h[n] = 0.f;
    float sumdv = 0.f;
    __syncthreads();
    float xn = xconv[((size_t)(b*LL + lsid[0]))*DIN + d];
    for (int c0 = 0; c0 < SL; c0 += 32) {
        for (int li = li0; li < 32; li += 2) {
            const float* dr = dts + ((size_t)bk*LL + l0 + c0 + li)*8;
            float aa = bdt;
            #pragma unroll
            for (int r = 0; r < RNK; ++r) aa += dr[r]*wdt[r];
            ldel[li*DIN + dd] = fmaxf(aa, 0.f) + __logf(1.f + __expf(-fabsf(aa)));
        }
        for (int e = t; e < 32*NST; e += 384)
            lB[e] = Bs[((size_t)bk*LL + l0 + c0)*NST + e];
        __syncthreads();
        if (fast) {
            for (int li2 = 0; li2 < 32; ++li2) {
                int li = c0 + li2;
                float xv = xn;
                if (li + 1 < SL) xn = xconv[((size_t)(b*LL + lsid[li+1]))*DIN + d];
                float dv = ldel[li2*DIN + d];
                sumdv += dv;
                float dxv = dv * xv;
                float4 b0 = *(const float4*)&lB[li2*NST + half*8];
                float4 b1 = *(const float4*)&lB[li2*NST + half*8 + 4];
                float bb[8] = {b0.x,b0.y,b0.z,b0.w, b1.x,b1.y,b1.z,b1.w};
                float P[8];
                float E1 = __expf(dv * Av0);
                P[0] = E1;       P[1] = E1*E1;   P[2] = P[1]*E1; P[3] = P[1]*P[1];
                P[4] = P[3]*E1;  P[5] = P[2]*P[2]; P[6] = P[5]*E1; P[7] = P[3]*P[3];
                float s = half ? P[7] : 1.0f;
                #pragma unroll
                for (int n = 0; n < 8; ++n)
                    h[n] = (s*P[n])*h[n] + dxv*bb[n];
            }
        } else {
            for (int li2 = 0; li2 < 32; ++li2) {
                int li = c0 + li2;
                float xv = xn;
                if (li + 1 < SL) xn = xconv[((size_t)(b*LL + lsid[li+1]))*DIN + d];
                float dv = ldel[li2*DIN + d];
                sumdv += dv;
                float dxv = dv * xv;
                float4 b0 = *(const float4*)&lB[li2*NST + half*8];
                float4 b1 = *(const float4*)&lB[li2*NST + half*8 + 4];
                float bb[8] = {b0.x,b0.y,b0.z,b0.w, b1.x,b1.y,b1.z,b1.w};
                #pragma unroll
                for (int n = 0; n < 8; ++n) {
                    float e2 = __expf(dv * Av[n]);
                    h[n] = e2*h[n] + dxv*bb[n];
                }
            }
        }
        __syncthreads();
    }
    float a[8];
    #pragma unroll
    for (int n = 0; n < 8; ++n) a[n] = __expf(Av[n]*sumdv);
    size_t base = (((size_t)bk*gridDim.x + seg)*DIN + d)*NST + half*8;
    *(float4*)&segA[base]     = make_float4(a[0],a[1],a[2],a[3]);
    *(float4*)&segA[base + 4] = make_float4(a[4],a[5],a[6],a[7]);
    *(float4*)&segB[base]     = make_float4(h[0],h[1],h[2],h[3]);
    *(float4*)&segB[base + 4] = make_float4(h[4],h[5],h[6],h[7]);
}

// ---------------------------------------------------------------------------
// K5: compose segment carries. Batched 8-wide loads (independent), then the
// dependent fma chain — breaks the 1-load-latency-per-step serialization.
__global__ __launch_bounds__(256) void k_scan2(const float* __restrict__ segA,
        const float* __restrict__ segB, float* __restrict__ hinit, int SEGC) {
    int idx = blockIdx.x*256 + threadIdx.x;
    if (idx >= BB*KK*DIN*NST) return;
    int bk = idx / (DIN*NST);
    int dn = idx % (DIN*NST);
    const size_t stride = DIN*NST;
    size_t o = (size_t)bk*SEGC*stride + dn;
    float h = 0.f;
    for (int s = 0; s < SEGC; s += 8) {
        float av[8], bv[8];
        #pragma unroll
        for (int j = 0; j < 8; ++j) {
            av[j] = segA[o + j*stride];
            bv[j] = segB[o + j*stride];
        }
        #pragma unroll
        for (int j = 0; j < 8; ++j) {
            hinit[o + j*stride] = h;
            h = av[j]*h + bv[j];
        }
        o += 8*stride;
    }
}

// ---------------------------------------------------------------------------
// K6: scan pass 3 — replay with h0, fast power path, pair-shfl y reduce.
__global__ __launch_bounds__(384) void k_scan3(const float* __restrict__ xconv,
        const float* __restrict__ Bs, const float* __restrict__ Cs,
        const float* __restrict__ dts, const float* __restrict__ dtw,
        const float* __restrict__ dtb,
        const int* __restrict__ scan_ids, const float* __restrict__ A_logs,
        const float* __restrict__ Ds, const float* __restrict__ hinit,
        float* __restrict__ y_dirs, float* __restrict__ poolsum, int SL) {
    __shared__ float ldel[32*DIN];
    __shared__ float lB[32*NST];
    __shared__ float lC[32*NST];
    __shared__ int lsid[256];
    int seg = blockIdx.x, bk = blockIdx.y;
    int b = bk >> 2, k = bk & 3;
    int t = threadIdx.x;
    int half = t & 1, d = t >> 1;
    int l0 = seg * SL;
    for (int i = t; i < SL; i += 384) lsid[i] = scan_ids[k*LL + l0 + i];
    float Av[8];
    {
        const float4* ap = (const float4*)(A_logs + ((k*DIN + d)*NST + half*8));
        float4 a0 = ap[0], a1 = ap[1];
        Av[0]=-__expf(a0.x); Av[1]=-__expf(a0.y); Av[2]=-__expf(a0.z); Av[3]=-__expf(a0.w);
        Av[4]=-__expf(a1.x); Av[5]=-__expf(a1.y); Av[6]=-__expf(a1.z); Av[7]=-__expf(a1.w);
    }
    float Av0 = -__expf(A_logs[(k*DIN + d)*NST]);
    bool okl = true;
    #pragma unroll
    for (int q = 0; q < 8; ++q) {
        float m = (float)(half*8 + q + 1);
        okl = okl && (fabsf(Av[q] - m*Av0) <= 1e-4f*m);
    }
    int fast = __all(okl);
    float Dv = Ds[k*DIN + d];
    int dd = t % DIN, li0 = t / DIN;
    float wdt[RNK];
    float bdt = dtb[k*DIN + dd];
    #pragma unroll
    for (int r = 0; r < RNK; ++r) wdt[r] = dtw[(k*DIN + dd)*RNK + r];
    float h[8];
    {
        size_t base = (((size_t)bk*gridDim.x + seg)*DIN + d)*NST + half*8;
        float4 h0 = *(const float4*)&hinit[base];
        float4 h1 = *(const float4*)&hinit[base + 4];
        h[0]=h0.x; h[1]=h0.y; h[2]=h0.z; h[3]=h0.w;
        h[4]=h1.x; h[5]=h1.y; h[6]=h1.z; h[7]=h1.w;
    }
    __syncthreads();
    float xn = xconv[((size_t)(b*LL + lsid[0]))*DIN + d];
    float pool = 0.f;
    for (int c0 = 0; c0 < SL; c0 += 32) {
        for (int li = li0; li < 32; li += 2) {
            const float* dr = dts + ((size_t)bk*LL + l0 + c0 + li)*8;
            float aa = bdt;
            #pragma unroll
            for (int r = 0; r < RNK; ++r) aa += dr[r]*wdt[r];
            ldel[li*DIN + dd] = fmaxf(aa, 0.f) + __logf(1.f + __expf(-fabsf(aa)));
        }
        for (int e = t; e < 32*NST; e += 384) {
            lB[e] = Bs[((size_t)bk*LL + l0 + c0)*NST + e];
            lC[e] = Cs[((size_t)bk*LL + l0 + c0)*NST + e];
        }
        __syncthreads();
        for (int li2 = 0; li2 < 32; ++li2) {
            int li = c0 + li2;
            int l = lsid[li];
            float xv = xn;
            if (li + 1 < SL) xn = xconv[((size_t)(b*LL + lsid[li+1]))*DIN + d];
            float dv = ldel[li2*DIN + d];
            float dxv = dv * xv;
            float4 b0 = *(const float4*)&lB[li2*NST + half*8];
            float4 b1 = *(const float4*)&lB[li2*NST + half*8 + 4];
            float4 c0v = *(const float4*)&lC[li2*NST + half*8];
            float4 c1v = *(const float4*)&lC[li2*NST + half*8 + 4];
            float bb[8] = {b0.x,b0.y,b0.z,b0.w, b1.x,b1.y,b1.z,b1.w};
            float cc[8] = {c0v.x,c0v.y,c0v.z,c0v.w, c1v.x,c1v.y,c1v.z,c1v.w};
            float y = 0.f;
            if (fast) {
                float P[8];
                float E1 = __expf(dv * Av0);
                P[0] = E1;       P[1] = E1*E1;     P[2] = P[1]*E1; P[3] = P[1]*P[1];
                P[4] = P[3]*E1;  P[5] = P[2]*P[2]; P[6] = P[5]*E1; P[7] = P[3]*P[3];
                float s = half ? P[7] : 1.0f;
                #pragma unroll
                for (int n = 0; n < 8; ++n) {
                    h[n] = (s*P[n])*h[n] + dxv*bb[n];
                    y += h[n]*cc[n];
                }
            } else {
                #pragma unroll
                for (int n = 0; n < 8; ++n) {
                    float e2 = __expf(dv * Av[n]);
                    h[n] = e2*h[n] + dxv*bb[n];
                    y += h[n]*cc[n];
                }
            }
            y += __shfl_xor(y, 1);
            if (half == 0) {
                y += xv * Dv;
                y_dirs[((size_t)(bk*LL + l))*DIN + d] = y;
                pool += y;
            }
        }
        __syncthreads();
    }
    if (half == 0) atomicAdd(&poolsum[(b*DIN + d)*KK + k], pool);
}

// ---------------------------------------------------------------------------
// K7: y = sum_k gate*y_dirs ; LN ; * silu(z) ; @ W_out^T. Gate computed
// in-block (fused, redundant per block — 768 sigmoids, trivial).
__global__ __launch_bounds__(256) void k_final(const float* __restrict__ y_dirs,
        const float* __restrict__ poolsum, const float* __restrict__ gw,
        const float* __restrict__ gb, const float* __restrict__ z_silu,
        const float* __restrict__ lng, const float* __restrict__ lnb,
        const float* __restrict__ Wout, float* __restrict__ out) {
    __shared__ float buf[16*193];
    __shared__ float lgate[DIN*KK];
    __shared__ float lmu[16], lrs[16];
    int b = blockIdx.y;
    int l0 = blockIdx.x * 16;
    int t = threadIdx.x;
    for (int e = t; e < DIN*KK; e += 256) {
        int d = e >> 2, o = e & 3;
        float acc = gb[d*KK + o];
        #pragma unroll
        for (int i = 0; i < KK; ++i)
            acc += (poolsum[(b*DIN + d)*KK + i] * (1.f/LL)) * gw[(d*KK + o)*KK + i];
        lgate[d*KK + o] = 1.f/(1.f + __expf(-acc));
    }
    __syncthreads();
    for (int i = 0; i < 12; ++i) {
        int e = t + 256*i;
        int d = e % DIN, l = e / DIN;
        float acc = 0.f;
        #pragma unroll
        for (int k = 0; k < KK; ++k)
            acc += y_dirs[((size_t)((b*KK + k)*LL + l0 + l))*DIN + d] * lgate[d*KK + k];
        buf[l*193 + d] = acc;
    }
    __syncthreads();
    int l2 = t >> 4, q = t & 15;
    float s = 0.f, s2 = 0.f;
    for (int i = 0; i < 12; ++i) {
        float v = buf[l2*193 + q + 16*i];
        s += v; s2 += v*v;
    }
    s += __shfl_xor(s, 1);  s2 += __shfl_xor(s2, 1);
    s += __shfl_xor(s, 2);  s2 += __shfl_xor(s2, 2);
    s += __shfl_xor(s, 4);  s2 += __shfl_xor(s2, 4);
    s += __shfl_xor(s, 8);  s2 += __shfl_xor(s2, 8);
    if (q == 0) {
        float mu = s * (1.f/DIN);
        float var = s2 * (1.f/DIN) - mu*mu;
        lmu[l2] = mu;
        lrs[l2] = rsqrtf(var + 1e-5f);
    }
    __syncthreads();
    for (int i = 0; i < 12; ++i) {
        int e = t + 256*i;
        int d = e % DIN, l = e / DIN;
        float v = buf[l*193 + d];
        float tv = (v - lmu[l]) * lrs[l] * lng[d] + lnb[d];
        tv *= z_silu[((size_t)(b*LL + l0 + l))*DIN + d];
        buf[l*193 + d] = tv;
    }
    __syncthreads();
    int l = t & 15;
    int c0 = (t >> 4) * 6;
    float acc[6];
    #pragma unroll
    for (int cc = 0; cc < 6; ++cc) acc[cc] = 0.f;
    for (int d = 0; d < DIN; ++d) {
        float v = buf[l*193 + d];
        #pragma unroll
        for (int cc = 0; cc < 6; ++cc)
            acc[cc] += v * Wout[(c0 + cc)*DIN + d];
    }
    #pragma unroll
    for (int cc = 0; cc < 6; ++cc)
        out[((size_t)(b*LL + l0 + l))*CC + c0 + cc] = acc[cc];
}

// ---------------------------------------------------------------------------
extern "C" void kernel_launch(void* const* d_in, const int* in_sizes, int n_in,
                              void* d_out, int out_size, void* d_ws, size_t ws_size,
                              hipStream_t stream) {
    const float* x      = (const float*)d_in[0];
    const float* W_in   = (const float*)d_in[1];
    const float* conv_w = (const float*)d_in[2];
    const float* conv_b = (const float*)d_in[3];
    const float* xpw    = (const float*)d_in[4];
    const float* dt_w   = (const float*)d_in[5];
    const float* dt_b   = (const float*)d_in[6];
    const float* A_logs = (const float*)d_in[7];
    const float* Ds     = (const float*)d_in[8];
    const float* gate_w = (const float*)d_in[9];
    const float* gate_b = (const float*)d_in[10];
    const float* ln_g   = (const float*)d_in[11];
    const float* ln_b   = (const float*)d_in[12];
    const float* W_out  = (const float*)d_in[13];
    const int* scan_ids = (const int*)d_in[14];
    float* out = (float*)d_out;

    const size_t baseF = 6291456ull + 2ull*1572864 + 262144ull + 2ull*524288 + 3072;
    int SEGC = 16;
    if ((baseF + 3ull*128*24576)*4 <= ws_size) SEGC = 128;
    else if ((baseF + 3ull*64*24576)*4 <= ws_size) SEGC = 64;
    else if ((baseF + 3ull*32*24576)*4 <= ws_size) SEGC = 32;
    int SL = LL / SEGC;
    size_t segF = (size_t)SEGC * 24576;

    float* ws      = (float*)d_ws;
    float* y_dirs  = ws;
    float* xc_pre  = ws;                       // alias (dead after k_conv)
    float* z_silu  = y_dirs  + 6291456;
    float* xconv   = z_silu  + 1572864;
    float* dts     = xconv   + 1572864;        // [bk][l][8]
    float* Bs      = dts     + 262144;
    float* Cs      = Bs      + 524288;
    float* poolsum = Cs      + 524288;
    float* segA    = poolsum + 3072;
    float* segB    = segA    + segF;
    float* hinit   = segB    + segF;

    hipMemsetAsync(poolsum, 0, 1536*sizeof(float), stream);

    k_inproj<<<dim3(LL/64, BB, 2), 256, 0, stream>>>(x, W_in, xc_pre, z_silu);
    k_conv<<<(BB*DIN*LL)/256, 256, 0, stream>>>(xc_pre, conv_w, conv_b, xconv);
    k_proj<<<dim3(LL/64, KK, BB), 512, 0, stream>>>(xconv, scan_ids, xpw,
                                                    dts, Bs, Cs);
    k_scan1<<<dim3(SEGC, BB*KK), 384, 0, stream>>>(xconv, Bs, dts, dt_w, dt_b,
                                                   scan_ids, A_logs, segA, segB, SL);
    k_scan2<<<(BB*KK*DIN*NST + 255)/256, 256, 0, stream>>>(segA, segB, hinit, SEGC);
    k_scan3<<<dim3(SEGC, BB*KK), 384, 0, stream>>>(xconv, Bs, Cs, dts, dt_w, dt_b,
                                                   scan_ids, A_logs, Ds, hinit,
                                                   y_dirs, poolsum, SL);
    k_final<<<dim3(LL/16, BB), 256, 0, stream>>>(y_dirs, poolsum, gate_w, gate_b,
                                                 z_silu, ln_g, ln_b, W_out, out);
}

// Round 7
// 277.854 us; speedup vs baseline: 2.0930x; 1.0184x over previous
//
#include <hip/hip_runtime.h>
#include <math.h>

#define BB 2
#define CC 96
#define DIN 192
#define NST 16
#define RNK 6
#define KK 4
#define LL 4096
#define RTOT (RNK + 2*NST)   // 38

// Scratch layouts:
//   xc_pre (aliases y_dirs), z_silu, xconv : [b][l][DIN]
//   dts    : [bk][l_scan][8]  (6 used)
//   Bs, Cs : [bk][l_scan][NST]
//   segA(/hinit alias)/segB : [bk][seg][d][NST]
//   y_dirs : [bk][l_spatial][DIN]   (pass1 writes partial y; k_apply adds h0 term)

// ---------------------------------------------------------------------------
// K1: in_proj, weights staged in LDS. 256 thr = 16 lg (4 l) x 16 og (12 oc).
__global__ __launch_bounds__(256) void k_inproj(const float* __restrict__ x,
        const float* __restrict__ W_in, float* __restrict__ xc_pre,
        float* __restrict__ z_silu) {
    __shared__ float lx[96*65];
    __shared__ float wt[48*196];
    int b = blockIdx.y, z = blockIdx.z;
    int l0 = blockIdx.x * 64;
    int t = threadIdx.x;
    for (int i = 0; i < 24; ++i) {
        int e = t + 256*i;
        int l = e / 96, c = e % 96;
        lx[c*65 + l] = x[((size_t)(b*LL + l0 + l))*96 + c];
    }
    int lg = t & 15;
    int og = t >> 4;
    float acc[4][12];
    #pragma unroll
    for (int j = 0; j < 4; ++j)
        #pragma unroll
        for (int q = 0; q < 12; ++q) acc[j][q] = 0.f;
    for (int p = 0; p < 2; ++p) {
        __syncthreads();
        for (int i = 0; i < 36; ++i) {
            int e = t + 256*i;
            int cc = e % 48, oc = e / 48;
            wt[cc*196 + oc] = W_in[((size_t)(z*192 + oc))*96 + p*48 + cc];
        }
        __syncthreads();
        #pragma unroll 2
        for (int cc = 0; cc < 48; ++cc) {
            int c = p*48 + cc;
            float x0 = lx[c*65 + 4*lg + 0];
            float x1 = lx[c*65 + 4*lg + 1];
            float x2 = lx[c*65 + 4*lg + 2];
            float x3 = lx[c*65 + 4*lg + 3];
            const float* wr = &wt[cc*196 + 12*og];
            float4 w0 = *(const float4*)(wr);
            float4 w1 = *(const float4*)(wr + 4);
            float4 w2 = *(const float4*)(wr + 8);
            float wv[12] = {w0.x,w0.y,w0.z,w0.w, w1.x,w1.y,w1.z,w1.w,
                            w2.x,w2.y,w2.z,w2.w};
            #pragma unroll
            for (int q = 0; q < 12; ++q) {
                acc[0][q] += x0*wv[q];
                acc[1][q] += x1*wv[q];
                acc[2][q] += x2*wv[q];
                acc[3][q] += x3*wv[q];
            }
        }
    }
    float* dst = (z == 0) ? xc_pre : z_silu;
    #pragma unroll
    for (int j = 0; j < 4; ++j) {
        int l = l0 + 4*lg + j;
        size_t base = (size_t)(b*LL + l)*DIN + 12*og;
        #pragma unroll
        for (int q = 0; q < 12; ++q) {
            float v = acc[j][q];
            if (z) v = v / (1.f + __expf(-v));
            dst[base + q] = v;
        }
    }
}

// ---------------------------------------------------------------------------
// K2: depthwise 3x3 conv + bias + SiLU, [l][d] in/out.
__global__ __launch_bounds__(256) void k_conv(const float* __restrict__ xc,
        const float* __restrict__ cw, const float* __restrict__ cb,
        float* __restrict__ out) {
    int gid = blockIdx.x*256 + threadIdx.x;
    int d = gid % DIN;
    int r = gid / DIN;
    int l = r & 4095, b = r >> 12;
    int w = l & 63, h = l >> 6;
    float acc = cb[d];
    #pragma unroll
    for (int dh = -1; dh <= 1; ++dh) {
        int h2 = h + dh;
        bool okh = (h2 >= 0) && (h2 < 64);
        #pragma unroll
        for (int dw = -1; dw <= 1; ++dw) {
            int w2 = w + dw;
            if (okh && w2 >= 0 && w2 < 64)
                acc += xc[((size_t)(b*LL + h2*64 + w2))*DIN + d] * cw[d*9 + (dh+1)*3 + (dw+1)];
        }
    }
    out[((size_t)(b*LL + l))*DIN + d] = acc / (1.f + __expf(-acc));
}

// ---------------------------------------------------------------------------
// K3: x_proj GEMV -> dts + Bs/Cs. Two d-phases of 96, LDS ~47 KB.
__global__ __launch_bounds__(512) void k_proj(const float* __restrict__ xconv,
        const int* __restrict__ scan_ids, const float* __restrict__ xpw,
        float* __restrict__ dts, float* __restrict__ Bs, float* __restrict__ Cs) {
    __shared__ float lxs[96*65];
    __shared__ float lw[RTOT*96];
    __shared__ float lbc[64*33];
    __shared__ int lsid[64];
    int k = blockIdx.y, b = blockIdx.z;
    int l0 = blockIdx.x * 64;
    int t = threadIdx.x;
    if (t < 64) lsid[t] = scan_ids[k*LL + l0 + t];
    int l = t & 63;
    int rg = __builtin_amdgcn_readfirstlane(t >> 6);
    float acc[5];
    #pragma unroll
    for (int j = 0; j < 5; ++j) acc[j] = 0.f;
    for (int p = 0; p < 2; ++p) {
        __syncthreads();
        for (int i = 0; i < 12; ++i) {
            int e = t + 512*i;
            int dd = e % 96, ll = e / 96;
            lxs[dd*65 + ll] = xconv[((size_t)(b*LL + lsid[ll]))*DIN + p*96 + dd];
        }
        for (int i = 0; i < 8; ++i) {
            int e = t + 512*i;
            if (e < RTOT*96) {
                int r = e / 96, dd = e % 96;
                lw[r*96 + dd] = xpw[(size_t)k*RTOT*DIN + r*DIN + p*96 + dd];
            }
        }
        __syncthreads();
        for (int dd = 0; dd < 96; dd += 4) {
            float x0 = lxs[(dd+0)*65 + l];
            float x1 = lxs[(dd+1)*65 + l];
            float x2 = lxs[(dd+2)*65 + l];
            float x3 = lxs[(dd+3)*65 + l];
            #pragma unroll
            for (int j = 0; j < 5; ++j) {
                int r = rg + 8*j;
                if (r < RTOT) {
                    float4 w = *(const float4*)&lw[r*96 + dd];
                    acc[j] += x0*w.x + x1*w.y + x2*w.z + x3*w.w;
                }
            }
        }
    }
    int bk = b*KK + k;
    #pragma unroll
    for (int j = 0; j < 5; ++j) {
        int r = rg + 8*j;
        if (r < RNK)       dts[((size_t)bk*LL + l0 + l)*8 + r] = acc[j];
        else if (r < RTOT) lbc[l*33 + (r - RNK)] = acc[j];
    }
    __syncthreads();
    size_t rowb = ((size_t)bk*LL + l0)*NST;
    for (int i = 0; i < 2; ++i) {
        int e = t + 512*i;
        int n = e & 15, ll = e >> 4;
        Bs[rowb + ll*NST + n] = lbc[ll*33 + n];
        Cs[rowb + ll*NST + n] = lbc[ll*33 + 16 + n];
    }
}

// ---------------------------------------------------------------------------
// K4: single heavy scan pass (h0 = 0). Writes PARTIAL y (C·hpart + x·D)
// scattered to spatial y_dirs, plus segment carries segA/segB.
// 384 thr = (d = t>>1) x (half = t&1, 8 states each). Plain-exp inner loop.
__global__ __launch_bounds__(384) void k_scan1(const float* __restrict__ xconv,
        const float* __restrict__ Bs, const float* __restrict__ Cs,
        const float* __restrict__ dts, const float* __restrict__ dtw,
        const float* __restrict__ dtb,
        const int* __restrict__ scan_ids, const float* __restrict__ A_logs,
        const float* __restrict__ Ds,
        float* __restrict__ y_dirs, float* __restrict__ segA,
        float* __restrict__ segB, int SL) {
    __shared__ float ldel[32*DIN];
    __shared__ float lB[32*NST];
    __shared__ float lC[32*NST];
    __shared__ int lsid[256];
    int seg = blockIdx.x, bk = blockIdx.y;
    int b = bk >> 2, k = bk & 3;
    int t = threadIdx.x;
    int half = t & 1, d = t >> 1;
    int l0 = seg * SL;
    for (int i = t; i < SL; i += 384) lsid[i] = scan_ids[k*LL + l0 + i];
    float Av[8];
    {
        const float4* ap = (const float4*)(A_logs + ((k*DIN + d)*NST + half*8));
        float4 a0 = ap[0], a1 = ap[1];
        Av[0]=-__expf(a0.x); Av[1]=-__expf(a0.y); Av[2]=-__expf(a0.z); Av[3]=-__expf(a0.w);
        Av[4]=-__expf(a1.x); Av[5]=-__expf(a1.y); Av[6]=-__expf(a1.z); Av[7]=-__expf(a1.w);
    }
    float Dv = Ds[k*DIN + d];
    int dd = t % DIN, li0 = t / DIN;
    float wdt[RNK];
    float bdt = dtb[k*DIN + dd];
    #pragma unroll
    for (int r = 0; r < RNK; ++r) wdt[r] = dtw[(k*DIN + dd)*RNK + r];
    float h[8];
    #pragma unroll
    for (int n = 0; n < 8; ++n) h[n] = 0.f;
    float sumdv = 0.f;
    __syncthreads();
    float xn = xconv[((size_t)(b*LL + lsid[0]))*DIN + d];
    for (int c0 = 0; c0 < SL; c0 += 32) {
        for (int li = li0; li < 32; li += 2) {
            const float* dr = dts + ((size_t)bk*LL + l0 + c0 + li)*8;
            float aa = bdt;
            #pragma unroll
            for (int r = 0; r < RNK; ++r) aa += dr[r]*wdt[r];
            ldel[li*DIN + dd] = fmaxf(aa, 0.f) + __logf(1.f + __expf(-fabsf(aa)));
        }
        for (int e = t; e < 32*NST; e += 384) {
            lB[e] = Bs[((size_t)bk*LL + l0 + c0)*NST + e];
            lC[e] = Cs[((size_t)bk*LL + l0 + c0)*NST + e];
        }
        __syncthreads();
        for (int li2 = 0; li2 < 32; ++li2) {
            int li = c0 + li2;
            int l = lsid[li];
            float xv = xn;
            if (li + 1 < SL) xn = xconv[((size_t)(b*LL + lsid[li+1]))*DIN + d];
            float dv = ldel[li2*DIN + d];
            sumdv += dv;
            float dxv = dv * xv;
            float4 b0 = *(const float4*)&lB[li2*NST + half*8];
            float4 b1 = *(const float4*)&lB[li2*NST + half*8 + 4];
            float4 c0v = *(const float4*)&lC[li2*NST + half*8];
            float4 c1v = *(const float4*)&lC[li2*NST + half*8 + 4];
            float bb[8] = {b0.x,b0.y,b0.z,b0.w, b1.x,b1.y,b1.z,b1.w};
            float cc[8] = {c0v.x,c0v.y,c0v.z,c0v.w, c1v.x,c1v.y,c1v.z,c1v.w};
            float y = 0.f;
            #pragma unroll
            for (int n = 0; n < 8; ++n) {
                float e2 = __expf(dv * Av[n]);
                h[n] = e2*h[n] + dxv*bb[n];
                y += h[n]*cc[n];
            }
            y += __shfl_xor(y, 1);
            if (half == 0) {
                y += xv * Dv;
                y_dirs[((size_t)(bk*LL + l))*DIN + d] = y;   // partial
            }
        }
        __syncthreads();
    }
    float a[8];
    #pragma unroll
    for (int n = 0; n < 8; ++n) a[n] = __expf(Av[n]*sumdv);
    size_t base = (((size_t)bk*gridDim.x + seg)*DIN + d)*NST + half*8;
    *(float4*)&segA[base]     = make_float4(a[0],a[1],a[2],a[3]);
    *(float4*)&segA[base + 4] = make_float4(a[4],a[5],a[6],a[7]);
    *(float4*)&segB[base]     = make_float4(h[0],h[1],h[2],h[3]);
    *(float4*)&segB[base + 4] = make_float4(h[4],h[5],h[6],h[7]);
}

// ---------------------------------------------------------------------------
// K5: compose segment carries. hinit ALIASES segA: batch-load av/bv first,
// then store hinit over segA (same thread, load-before-store order).
__global__ __launch_bounds__(256) void k_scan2(const float* segA,
        const float* segB, float* hinit, int SEGC) {
    int idx = blockIdx.x*256 + threadIdx.x;
    if (idx >= BB*KK*DIN*NST) return;
    int bk = idx / (DIN*NST);
    int dn = idx % (DIN*NST);
    const size_t stride = DIN*NST;
    size_t o = (size_t)bk*SEGC*stride + dn;
    float h = 0.f;
    for (int s = 0; s < SEGC; s += 8) {
        float av[8], bv[8];
        #pragma unroll
        for (int j = 0; j < 8; ++j) {
            av[j] = segA[o + j*stride];
            bv[j] = segB[o + j*stride];
        }
        #pragma unroll
        for (int j = 0; j < 8; ++j) {
            hinit[o + j*stride] = h;
            h = av[j]*h + bv[j];
        }
        o += 8*stride;
    }
}

// ---------------------------------------------------------------------------
// K6: apply h0 correction:  y[l] += sum_n C[l,n] * h0[n] * exp(Av[n]*cum[l]).
// No recurrence (cum is a scalar running sum). Fast path (A[n]=(n+1)A0,
// verified): 1 exp + Horner. Also computes pool of the FINAL y.
__global__ __launch_bounds__(384) void k_apply(const float* __restrict__ Cs,
        const float* __restrict__ dts, const float* __restrict__ dtw,
        const float* __restrict__ dtb,
        const int* __restrict__ scan_ids, const float* __restrict__ A_logs,
        const float* __restrict__ hinit,
        float* __restrict__ y_dirs, float* __restrict__ poolsum, int SL) {
    __shared__ float ldel[32*DIN];
    __shared__ float lC[32*NST];
    __shared__ int lsid[256];
    int seg = blockIdx.x, bk = blockIdx.y;
    int b = bk >> 2, k = bk & 3;
    int t = threadIdx.x;
    int half = t & 1, d = t >> 1;
    int l0 = seg * SL;
    for (int i = t; i < SL; i += 384) lsid[i] = scan_ids[k*LL + l0 + i];
    float Av[8];
    {
        const float4* ap = (const float4*)(A_logs + ((k*DIN + d)*NST + half*8));
        float4 a0 = ap[0], a1 = ap[1];
        Av[0]=-__expf(a0.x); Av[1]=-__expf(a0.y); Av[2]=-__expf(a0.z); Av[3]=-__expf(a0.w);
        Av[4]=-__expf(a1.x); Av[5]=-__expf(a1.y); Av[6]=-__expf(a1.z); Av[7]=-__expf(a1.w);
    }
    float Av0 = -__expf(A_logs[(k*DIN + d)*NST]);
    bool okl = true;
    #pragma unroll
    for (int q = 0; q < 8; ++q) {
        float m = (float)(half*8 + q + 1);
        okl = okl && (fabsf(Av[q] - m*Av0) <= 1e-4f*m);
    }
    int fast = __all(okl);
    float h0[8];
    {
        size_t base = (((size_t)bk*gridDim.x + seg)*DIN + d)*NST + half*8;
        float4 v0 = *(const float4*)&hinit[base];
        float4 v1 = *(const float4*)&hinit[base + 4];
        h0[0]=v0.x; h0[1]=v0.y; h0[2]=v0.z; h0[3]=v0.w;
        h0[4]=v1.x; h0[5]=v1.y; h0[6]=v1.z; h0[7]=v1.w;
    }
    int dd = t % DIN, li0 = t / DIN;
    float wdt[RNK];
    float bdt = dtb[k*DIN + dd];
    #pragma unroll
    for (int r = 0; r < RNK; ++r) wdt[r] = dtw[(k*DIN + dd)*RNK + r];
    float cum = 0.f;
    float pool = 0.f;
    __syncthreads();
    for (int c0 = 0; c0 < SL; c0 += 32) {
        for (int li = li0; li < 32; li += 2) {
            const float* dr = dts + ((size_t)bk*LL + l0 + c0 + li)*8;
            float aa = bdt;
            #pragma unroll
            for (int r = 0; r < RNK; ++r) aa += dr[r]*wdt[r];
            ldel[li*DIN + dd] = fmaxf(aa, 0.f) + __logf(1.f + __expf(-fabsf(aa)));
        }
        for (int e = t; e < 32*NST; e += 384)
            lC[e] = Cs[((size_t)bk*LL + l0 + c0)*NST + e];
        __syncthreads();
        for (int li2 = 0; li2 < 32; ++li2) {
            int li = c0 + li2;
            int l = lsid[li];
            cum += ldel[li2*DIN + d];
            float4 c0v = *(const float4*)&lC[li2*NST + half*8];
            float4 c1v = *(const float4*)&lC[li2*NST + half*8 + 4];
            float cc[8] = {c0v.x,c0v.y,c0v.z,c0v.w, c1v.x,c1v.y,c1v.z,c1v.w};
            float g;
            if (fast) {
                float E = __expf(Av0 * cum);
                g = 0.f;
                #pragma unroll
                for (int q = 7; q >= 0; --q) g = g*E + cc[q]*h0[q];
                g *= E;
                if (half) {
                    float E2 = E*E, E4 = E2*E2;
                    g *= E4*E4;
                }
            } else {
                g = 0.f;
                #pragma unroll
                for (int q = 0; q < 8; ++q)
                    g += cc[q]*h0[q]*__expf(Av[q]*cum);
            }
            g += __shfl_xor(g, 1);
            if (half == 0) {
                size_t yo = ((size_t)(bk*LL + l))*DIN + d;
                float y = y_dirs[yo] + g;
                y_dirs[yo] = y;
                pool += y;
            }
        }
        __syncthreads();
    }
    if (half == 0) atomicAdd(&poolsum[(b*DIN + d)*KK + k], pool);
}

// ---------------------------------------------------------------------------
// K7: y = sum_k gate*y_dirs ; LN ; * silu(z) ; @ W_out^T. Gate fused in-block.
__global__ __launch_bounds__(256) void k_final(const float* __restrict__ y_dirs,
        const float* __restrict__ poolsum, const float* __restrict__ gw,
        const float* __restrict__ gb, const float* __restrict__ z_silu,
        const float* __restrict__ lng, const float* __restrict__ lnb,
        const float* __restrict__ Wout, float* __restrict__ out) {
    __shared__ float buf[16*193];
    __shared__ float lgate[DIN*KK];
    __shared__ float lmu[16], lrs[16];
    int b = blockIdx.y;
    int l0 = blockIdx.x * 16;
    int t = threadIdx.x;
    for (int e = t; e < DIN*KK; e += 256) {
        int d = e >> 2, o = e & 3;
        float acc = gb[d*KK + o];
        #pragma unroll
        for (int i = 0; i < KK; ++i)
            acc += (poolsum[(b*DIN + d)*KK + i] * (1.f/LL)) * gw[(d*KK + o)*KK + i];
        lgate[d*KK + o] = 1.f/(1.f + __expf(-acc));
    }
    __syncthreads();
    for (int i = 0; i < 12; ++i) {
        int e = t + 256*i;
        int d = e % DIN, l = e / DIN;
        float acc = 0.f;
        #pragma unroll
        for (int k = 0; k < KK; ++k)
            acc += y_dirs[((size_t)((b*KK + k)*LL + l0 + l))*DIN + d] * lgate[d*KK + k];
        buf[l*193 + d] = acc;
    }
    __syncthreads();
    int l2 = t >> 4, q = t & 15;
    float s = 0.f, s2 = 0.f;
    for (int i = 0; i < 12; ++i) {
        float v = buf[l2*193 + q + 16*i];
        s += v; s2 += v*v;
    }
    s += __shfl_xor(s, 1);  s2 += __shfl_xor(s2, 1);
    s += __shfl_xor(s, 2);  s2 += __shfl_xor(s2, 2);
    s += __shfl_xor(s, 4);  s2 += __shfl_xor(s2, 4);
    s += __shfl_xor(s, 8);  s2 += __shfl_xor(s2, 8);
    if (q == 0) {
        float mu = s * (1.f/DIN);
        float var = s2 * (1.f/DIN) - mu*mu;
        lmu[l2] = mu;
        lrs[l2] = rsqrtf(var + 1e-5f);
    }
    __syncthreads();
    for (int i = 0; i < 12; ++i) {
        int e = t + 256*i;
        int d = e % DIN, l = e / DIN;
        float v = buf[l*193 + d];
        float tv = (v - lmu[l]) * lrs[l] * lng[d] + lnb[d];
        tv *= z_silu[((size_t)(b*LL + l0 + l))*DIN + d];
        buf[l*193 + d] = tv;
    }
    __syncthreads();
    int l = t & 15;
    int c0 = (t >> 4) * 6;
    float acc[6];
    #pragma unroll
    for (int cc = 0; cc < 6; ++cc) acc[cc] = 0.f;
    for (int d = 0; d < DIN; ++d) {
        float v = buf[l*193 + d];
        #pragma unroll
        for (int cc = 0; cc < 6; ++cc)
            acc[cc] += v * Wout[(c0 + cc)*DIN + d];
    }
    #pragma unroll
    for (int cc = 0; cc < 6; ++cc)
        out[((size_t)(b*LL + l0 + l))*CC + c0 + cc] = acc[cc];
}

// ---------------------------------------------------------------------------
extern "C" void kernel_launch(void* const* d_in, const int* in_sizes, int n_in,
                              void* d_out, int out_size, void* d_ws, size_t ws_size,
                              hipStream_t stream) {
    const float* x      = (const float*)d_in[0];
    const float* W_in   = (const float*)d_in[1];
    const float* conv_w = (const float*)d_in[2];
    const float* conv_b = (const float*)d_in[3];
    const float* xpw    = (const float*)d_in[4];
    const float* dt_w   = (const float*)d_in[5];
    const float* dt_b   = (const float*)d_in[6];
    const float* A_logs = (const float*)d_in[7];
    const float* Ds     = (const float*)d_in[8];
    const float* gate_w = (const float*)d_in[9];
    const float* gate_b = (const float*)d_in[10];
    const float* ln_g   = (const float*)d_in[11];
    const float* ln_b   = (const float*)d_in[12];
    const float* W_out  = (const float*)d_in[13];
    const int* scan_ids = (const int*)d_in[14];
    float* out = (float*)d_out;

    // Scratch: y_dirs + z + xconv + dts + Bs + Cs + pool + 2 seg buffers
    // (hinit aliases segA).  @SEGC=128: ~68 MB.
    const size_t baseF = 6291456ull + 2ull*1572864 + 262144ull + 2ull*524288 + 3072;
    int SEGC = 16;
    if ((baseF + 2ull*128*24576)*4 <= ws_size) SEGC = 128;
    else if ((baseF + 2ull*64*24576)*4 <= ws_size) SEGC = 64;
    else if ((baseF + 2ull*32*24576)*4 <= ws_size) SEGC = 32;
    int SL = LL / SEGC;
    size_t segF = (size_t)SEGC * 24576;

    float* ws      = (float*)d_ws;
    float* y_dirs  = ws;
    float* xc_pre  = ws;                       // alias (dead after k_conv)
    float* z_silu  = y_dirs  + 6291456;
    float* xconv   = z_silu  + 1572864;
    float* dts     = xconv   + 1572864;        // [bk][l][8]
    float* Bs      = dts     + 262144;
    float* Cs      = Bs      + 524288;
    float* poolsum = Cs      + 524288;
    float* segA    = poolsum + 3072;
    float* segB    = segA    + segF;
    float* hinit   = segA;                     // ALIAS (scan2 is alias-safe)

    hipMemsetAsync(poolsum, 0, 1536*sizeof(float), stream);

    k_inproj<<<dim3(LL/64, BB, 2), 256, 0, stream>>>(x, W_in, xc_pre, z_silu);
    k_conv<<<(BB*DIN*LL)/256, 256, 0, stream>>>(xc_pre, conv_w, conv_b, xconv);
    k_proj<<<dim3(LL/64, KK, BB), 512, 0, stream>>>(xconv, scan_ids, xpw,
                                                    dts, Bs, Cs);
    k_scan1<<<dim3(SEGC, BB*KK), 384, 0, stream>>>(xconv, Bs, Cs, dts, dt_w, dt_b,
                                                   scan_ids, A_logs, Ds,
                                                   y_dirs, segA, segB, SL);
    k_scan2<<<(BB*KK*DIN*NST + 255)/256, 256, 0, stream>>>(segA, segB, hinit, SEGC);
    k_apply<<<dim3(SEGC, BB*KK), 384, 0, stream>>>(Cs, dts, dt_w, dt_b,
                                                   scan_ids, A_logs, hinit,
                                                   y_dirs, poolsum, SL);
    k_final<<<dim3(LL/16, BB), 256, 0, stream>>>(y_dirs, poolsum, gate_w, gate_b,
                                                 z_silu, ln_g, ln_b, W_out, out);
}